// Round 10
// baseline (679.044 us; speedup 1.0000x reference)
//
#include <hip/hip_runtime.h>
#include <hip/hip_bf16.h>

typedef unsigned short ushort_t;
typedef __attribute__((ext_vector_type(8))) short short8;
typedef __attribute__((ext_vector_type(4))) float f32x4;

__device__ __forceinline__ float bf2f(unsigned short u) {
  union { unsigned int i; float f; } v; v.i = ((unsigned int)u) << 16; return v.f;
}
__device__ __forceinline__ unsigned short f2bf(float f) {
  union { float f; unsigned int i; } v; v.f = f;
  unsigned int u = v.i;
  unsigned int r = (u + 0x7fffu + ((u >> 16) & 1u)) >> 16;
  return (unsigned short)r;
}

__device__ __forceinline__ void gload16(const void* g, void* l) {
  __builtin_amdgcn_global_load_lds(
      (const __attribute__((address_space(1))) void*)g,
      (__attribute__((address_space(3))) void*)l, 16, 0, 0);
}

// ============ R3-structure 128x128 kernel, 4 blocks/CU (proven point) ============
// NOTE: (256,5) spills — 60 VGPR + 64 AGPR acc = 124 regs needs the 4-wave/SIMD
// 128-reg budget. R8 measured the spill as +34MB WRITE_SIZE and 1.5x dur.
template<int KTOT, int ACT, bool RES>
__global__ __launch_bounds__(256, 4) void gemm_kernel(
    const ushort_t* __restrict__ A, const ushort_t* __restrict__ W,
    const float* __restrict__ bias,
    const ushort_t* __restrict__ resin, const float* __restrict__ resbias,
    ushort_t* __restrict__ out,
    int M, int Ntot, int T_in, int T_out, int sh1, int ncb)
{
  constexpr int AROW = (KTOT == 1024) ? 512 : KTOT;
  __shared__ ushort_t As[128 * 64];
  __shared__ ushort_t Ws[128 * 64];

  const int tid = threadIdx.x;
  const int lane = tid & 63;
  const int w = tid >> 6;
  const int wm = w >> 1, wn = w & 1;

  // XCD-chunked block swizzle (bijective, m204)
  const int nblocks = (int)gridDim.x;
  const int xcd = blockIdx.x & 7, kk = blockIdx.x >> 3;
  const int q = nblocks >> 3, rr = nblocks & 7;
  const int L = xcd * q + (xcd < rr ? xcd : rr) + kk;
  int rowblk, colblk;
  if (ncb == 4) { rowblk = L >> 2; colblk = L & 3; }
  else          { rowblk = L;      colblk = 0; }
  const int blockN = colblk * 128;
  const int blockRow = rowblk * 128;

  const int b0 = blockRow / T_out;
  const int t0 = blockRow - b0 * T_out;

  f32x4 acc[4][4];
#pragma unroll
  for (int i = 0; i < 4; ++i)
#pragma unroll
    for (int j = 0; j < 4; ++j) acc[i][j] = f32x4{0.f, 0.f, 0.f, 0.f};

  const int mloc = tid >> 3;
  const int csw = (((tid & 7) ^ ((tid >> 3) & 7))) * 8;  // T2 pre-swizzled src chunk

  for (int k0 = 0; k0 < KTOT; k0 += 64) {
    const int kcol = k0 & (AROW - 1);
    const int rowoff = (KTOT == 1024 && k0 >= 512) ? sh1 : 0;
#pragma unroll
    for (int j = 0; j < 4; ++j) {
      int m = j * 32 + mloc;
      int r = blockRow + m;
      int t = t0 + m;
      int bb = b0;
      if (t >= T_out) { ++bb; t -= T_out; }
      long grow = (r < M) ? ((long)bb * T_in + t + rowoff)
                          : ((long)b0 * T_in + t0 + rowoff);
      gload16(A + grow * AROW + kcol + csw, (char*)As + (j * 4096 + tid * 16));
    }
#pragma unroll
    for (int j = 0; j < 4; ++j) {
      int n = blockN + j * 32 + mloc;
      gload16(W + (long)n * KTOT + k0 + csw, (char*)Ws + (j * 4096 + tid * 16));
    }
    __syncthreads();
#pragma unroll
    for (int ks = 0; ks < 64; ks += 32) {
      short8 af[4], bf[4];
      const int hi = lane >> 4;
      const int rlo = lane & 15;
#pragma unroll
      for (int f = 0; f < 4; ++f) {
        int row = wm * 64 + f * 16 + rlo;
        int chunk = (ks >> 3) + hi;
        af[f] = *reinterpret_cast<const short8*>(
            (const char*)As + row * 128 + ((chunk ^ (row & 7)) << 4));
      }
#pragma unroll
      for (int f = 0; f < 4; ++f) {
        int row = wn * 64 + f * 16 + rlo;
        int chunk = (ks >> 3) + hi;
        bf[f] = *reinterpret_cast<const short8*>(
            (const char*)Ws + row * 128 + ((chunk ^ (row & 7)) << 4));
      }
#pragma unroll
      for (int fm = 0; fm < 4; ++fm)
#pragma unroll
        for (int fn = 0; fn < 4; ++fn)
          acc[fm][fn] = __builtin_amdgcn_mfma_f32_16x16x32_bf16(af[fm], bf[fn], acc[fm][fn], 0, 0, 0);
    }
    __syncthreads();
  }

  const int colb = lane & 15;
  const int rowb = (lane >> 4) * 4;
  float bv[4];
#pragma unroll
  for (int fn = 0; fn < 4; ++fn) {
    int col = blockN + wn * 64 + fn * 16 + colb;
    float b = bias ? bias[col] : 0.f;
    if (RES) b += resbias[col];
    bv[fn] = b;
  }
#pragma unroll
  for (int fm = 0; fm < 4; ++fm) {
#pragma unroll
    for (int reg = 0; reg < 4; ++reg) {
      int r = blockRow + wm * 64 + fm * 16 + rowb + reg;
      if (r < M) {
#pragma unroll
        for (int fn = 0; fn < 4; ++fn) {
          int col = blockN + wn * 64 + fn * 16 + colb;
          float v = acc[fm][fn][reg] + bv[fn];
          if (RES) v += bf2f(resin[(long)r * 512 + col]);
          if (ACT == 1) v = fmaxf(v, 0.f);
          else if (ACT == 2) v = tanhf(v);
          out[(long)r * Ntot + col] = f2bf(v);
        }
      }
    }
  }
}

// ============ fused bnf + s1 kernel (32 KB LDS -> 4 blocks/CU) ============
// Phase 1: H = A @ Wb^T + bb (K=512, N=128) -> bufB (HBM) + Hs (LDS, swizzled).
//          As/Ws live in smem[0..16K)/[16K..32K).
// Phase 2: S = tanh(H @ W1^T) (K=128). Hs OVERLAYS As+Ws (dead after phase-1
//          barrier); W1 fragments are read per-lane from GLOBAL (32 KB,
//          L2-resident, broadcast across blocks) — no LDS staging.
__global__ __launch_bounds__(256, 4) void bnf_s1_kernel(
    const ushort_t* __restrict__ A, const ushort_t* __restrict__ Wb,
    const float* __restrict__ bb, const ushort_t* __restrict__ W1,
    ushort_t* __restrict__ outH, ushort_t* __restrict__ outS)
{
  __shared__ char smem[32768];
  ushort_t* As = (ushort_t*)smem;            // phase 1
  ushort_t* Ws = (ushort_t*)(smem + 16384);  // phase 1
  char* Hs = smem;                           // phase 2 overlay: 128 rows x 256 B

  const int tid = threadIdx.x;
  const int lane = tid & 63;
  const int w = tid >> 6;
  const int wm = w >> 1, wn = w & 1;
  const int blockRow = blockIdx.x * 128;

  const int mloc = tid >> 3;
  const int csw = (((tid & 7) ^ ((tid >> 3) & 7))) * 8;
  const int rlo = lane & 15, hi = lane >> 4;
  const int colb = lane & 15, rowb = (lane >> 4) * 4;

  f32x4 acc[4][4];
#pragma unroll
  for (int i = 0; i < 4; ++i)
#pragma unroll
    for (int j = 0; j < 4; ++j) acc[i][j] = f32x4{0.f, 0.f, 0.f, 0.f};

  // ---- phase 1: bnf GEMM ----
  for (int k0 = 0; k0 < 512; k0 += 64) {
#pragma unroll
    for (int j = 0; j < 4; ++j) {
      long r = blockRow + j * 32 + mloc;
      gload16(A + r * 512 + k0 + csw, (char*)As + (j * 4096 + tid * 16));
    }
#pragma unroll
    for (int j = 0; j < 4; ++j) {
      int n = j * 32 + mloc;
      gload16(Wb + (long)n * 512 + k0 + csw, (char*)Ws + (j * 4096 + tid * 16));
    }
    __syncthreads();
#pragma unroll
    for (int ks = 0; ks < 64; ks += 32) {
      short8 af[4], bf[4];
#pragma unroll
      for (int f = 0; f < 4; ++f) {
        int row = wm * 64 + f * 16 + rlo;
        int chunk = (ks >> 3) + hi;
        af[f] = *reinterpret_cast<const short8*>(
            (const char*)As + row * 128 + ((chunk ^ (row & 7)) << 4));
      }
#pragma unroll
      for (int f = 0; f < 4; ++f) {
        int row = wn * 64 + f * 16 + rlo;
        int chunk = (ks >> 3) + hi;
        bf[f] = *reinterpret_cast<const short8*>(
            (const char*)Ws + row * 128 + ((chunk ^ (row & 7)) << 4));
      }
#pragma unroll
      for (int fm = 0; fm < 4; ++fm)
#pragma unroll
        for (int fn = 0; fn < 4; ++fn)
          acc[fm][fn] = __builtin_amdgcn_mfma_f32_16x16x32_bf16(af[fm], bf[fn], acc[fm][fn], 0, 0, 0);
    }
    __syncthreads();   // As/Ws dead from here on -> Hs may overlay
  }

  // epilogue 1: H -> HBM + Hs (swizzled, overlaying As/Ws)
#pragma unroll
  for (int fm = 0; fm < 4; ++fm) {
#pragma unroll
    for (int reg = 0; reg < 4; ++reg) {
      int rl = wm * 64 + fm * 16 + rowb + reg;
      long r = blockRow + rl;
#pragma unroll
      for (int fn = 0; fn < 4; ++fn) {
        int col = wn * 64 + fn * 16 + colb;
        float v = acc[fm][fn][reg] + bb[col];
        ushort_t us = f2bf(v);
        outH[r * 128 + col] = us;
        int ch = col >> 3;          // 16B chunk 0..15
        ((ushort_t*)(Hs + rl * 256 + ((ch ^ (rl & 7)) << 4)))[col & 7] = us;
      }
    }
  }
  __syncthreads();

  // ---- phase 2: s1 = tanh(H @ W1^T), K=128; W1 frags straight from global ----
  f32x4 acc2[4][4];
#pragma unroll
  for (int i = 0; i < 4; ++i)
#pragma unroll
    for (int j = 0; j < 4; ++j) acc2[i][j] = f32x4{0.f, 0.f, 0.f, 0.f};
#pragma unroll
  for (int kt = 0; kt < 2; ++kt) {
#pragma unroll
    for (int ks = 0; ks < 64; ks += 32) {
      short8 af[4], bf[4];
#pragma unroll
      for (int f = 0; f < 4; ++f) {
        int row = wm * 64 + f * 16 + rlo;
        int ch = kt * 8 + (ks >> 3) + hi;   // 0..15 within Hs row
        af[f] = *reinterpret_cast<const short8*>(
            Hs + row * 256 + ((ch ^ (row & 7)) << 4));
      }
#pragma unroll
      for (int f = 0; f < 4; ++f) {
        int row = wn * 64 + f * 16 + rlo;
        bf[f] = *reinterpret_cast<const short8*>(
            W1 + (long)row * 128 + kt * 64 + ks + hi * 8);
      }
#pragma unroll
      for (int fm = 0; fm < 4; ++fm)
#pragma unroll
        for (int fn = 0; fn < 4; ++fn)
          acc2[fm][fn] = __builtin_amdgcn_mfma_f32_16x16x32_bf16(af[fm], bf[fn], acc2[fm][fn], 0, 0, 0);
    }
  }
#pragma unroll
  for (int fm = 0; fm < 4; ++fm) {
#pragma unroll
    for (int reg = 0; reg < 4; ++reg) {
      long r = blockRow + wm * 64 + fm * 16 + rowb + reg;
#pragma unroll
      for (int fn = 0; fn < 4; ++fn) {
        int col = wn * 64 + fn * 16 + colb;
        outS[r * 128 + col] = f2bf(tanhf(acc2[fm][fn][reg]));
      }
    }
  }
}

__global__ __launch_bounds__(256) void pad512_f32_kernel(
    const float* __restrict__ in, ushort_t* __restrict__ out, long total, int Kin)
{
  long g = ((long)blockIdx.x * 256 + threadIdx.x) * 4;
  if (g >= total) return;
  int r = (int)(g >> 9), c = (int)(g & 511);
  ushort_t o0 = 0, o1 = 0, o2 = 0, o3 = 0;
  if (c < Kin) {
    float4 v = *(const float4*)(in + (long)r * Kin + c);
    o0 = f2bf(v.x); o1 = f2bf(v.y); o2 = f2bf(v.z); o3 = f2bf(v.w);
  }
  unsigned long long pk = (unsigned long long)o0 | ((unsigned long long)o1 << 16) |
                          ((unsigned long long)o2 << 32) | ((unsigned long long)o3 << 48);
  *(unsigned long long*)(out + g) = pk;
}

__global__ __launch_bounds__(256) void repack_tdnn_f32_kernel(
    const float* __restrict__ in, ushort_t* __restrict__ out)
{
  int g = blockIdx.x * 256 + threadIdx.x;
  int o = g >> 10, rem = g & 1023;
  int s = rem >> 9, i = rem & 511;
  out[g] = f2bf(in[(o << 10) + (i << 1) + s]);
}

__global__ __launch_bounds__(256) void cvt_kernel(
    const float* __restrict__ in, ushort_t* __restrict__ out, int n)
{
  int g = (blockIdx.x * 256 + threadIdx.x) * 4;
  if (g >= n) return;
  float4 v = *(const float4*)(in + g);
  unsigned long long pk = (unsigned long long)f2bf(v.x) | ((unsigned long long)f2bf(v.y) << 16) |
                          ((unsigned long long)f2bf(v.z) << 32) | ((unsigned long long)f2bf(v.w) << 48);
  *(unsigned long long*)(out + g) = pk;
}

// one block per (batch, head): scores -> softmax over t -> At (f32)
__global__ __launch_bounds__(256) void attn_kernel(
    const ushort_t* __restrict__ s1, const float* __restrict__ ws2,
    float* __restrict__ At_out, int T)
{
  __shared__ float sc[800];
  __shared__ float w2s[128];
  __shared__ float redm[4], reds[4];
  const int b = blockIdx.x / 5, h = blockIdx.x % 5;
  const int tid = threadIdx.x;
  const int lane = tid & 63, wv = tid >> 6;
  if (tid < 128) w2s[tid] = ws2[h * 128 + tid];
  __syncthreads();
  for (int t = tid; t < T; t += 256) {
    const ushort_t* row = s1 + ((long)b * T + t) * 128;
    float a = 0.f;
    for (int c = 0; c < 128; c += 8) {
      short8 v = *reinterpret_cast<const short8*>(row + c);
#pragma unroll
      for (int j = 0; j < 8; ++j) a += bf2f((unsigned short)v[j]) * w2s[c + j];
    }
    sc[t] = a;
  }
  __syncthreads();
  float m = -1e30f;
  for (int t = tid; t < T; t += 256) m = fmaxf(m, sc[t]);
#pragma unroll
  for (int off = 32; off > 0; off >>= 1) m = fmaxf(m, __shfl_xor(m, off));
  if (lane == 0) redm[wv] = m;
  __syncthreads();
  m = fmaxf(fmaxf(redm[0], redm[1]), fmaxf(redm[2], redm[3]));
  float s = 0.f;
  for (int t = tid; t < T; t += 256) s += expf(sc[t] - m);
#pragma unroll
  for (int off = 32; off > 0; off >>= 1) s += __shfl_xor(s, off);
  if (lane == 0) reds[wv] = s;
  __syncthreads();
  s = reds[0] + reds[1] + reds[2] + reds[3];
  float inv = 1.f / s;
  long base = ((long)b * 5 + h) * T;
  for (int t = tid; t < T; t += 256)
    At_out[base + t] = expf(sc[t] - m) * inv;
}

__global__ __launch_bounds__(640) void pool_kernel(
    const float* __restrict__ At_f, const ushort_t* __restrict__ hb,
    float* __restrict__ pooled, int T)
{
  int b = blockIdx.x, tid = threadIdx.x;
  int h = tid >> 7, d = tid & 127;
  const float* at = At_f + ((long)b * 5 + h) * T;
  const ushort_t* hr = hb + (long)b * T * 128 + d;
  float acc = 0.f;
  int t = 0;
  for (; t + 4 <= T; t += 4) {
    acc += at[t]     * bf2f(hr[(long)(t) * 128]);
    acc += at[t + 1] * bf2f(hr[(long)(t + 1) * 128]);
    acc += at[t + 2] * bf2f(hr[(long)(t + 2) * 128]);
    acc += at[t + 3] * bf2f(hr[(long)(t + 3) * 128]);
  }
  for (; t < T; ++t) acc += at[t] * bf2f(hr[(long)t * 128]);
  pooled[b * 640 + tid] = acc;
}

__global__ __launch_bounds__(128) void head_kernel(
    const float* __restrict__ pooled, const float* __restrict__ w,
    const float* __restrict__ bias, float* __restrict__ out)
{
  int b = blockIdx.x, o = threadIdx.x;
  const float* wr = w + o * 640;
  const float* p = pooled + b * 640;
  float acc = bias[o];
  for (int i = 0; i < 640; i += 4)
    acc += p[i] * wr[i] + p[i + 1] * wr[i + 1] +
           p[i + 2] * wr[i + 2] + p[i + 3] * wr[i + 3];
  out[b * 128 + o] = fmaxf(acc, 0.f);
}

extern "C" void kernel_launch(void* const* d_in, const int* in_sizes, int n_in,
                              void* d_out, int out_size, void* d_ws, size_t ws_size,
                              hipStream_t stream)
{
  (void)in_sizes; (void)n_in; (void)out_size; (void)ws_size;
  const float* x     = (const float*)d_in[0];
  const float* fc1_w = (const float*)d_in[1];
  const float* fc1_b = (const float*)d_in[2];
  const float *rw1[4], *rb1[4], *rw2[4], *rb2[4], *rbias[4];
  for (int i = 0; i < 4; ++i) {
    rw1[i]   = (const float*)d_in[3 + 5 * i + 0];
    rb1[i]   = (const float*)d_in[3 + 5 * i + 1];
    rw2[i]   = (const float*)d_in[3 + 5 * i + 2];
    rb2[i]   = (const float*)d_in[3 + 5 * i + 3];
    rbias[i] = (const float*)d_in[3 + 5 * i + 4];
  }
  const float *tk[3], *tb[3];
  for (int i = 0; i < 3; ++i) {
    tk[i] = (const float*)d_in[23 + 2 * i];
    tb[i] = (const float*)d_in[24 + 2 * i];
  }
  const float* bnf_w = (const float*)d_in[29];
  const float* bnf_b = (const float*)d_in[30];
  const float* ws1   = (const float*)d_in[31];
  const float* ws2   = (const float*)d_in[32];
  const float* bnw_w = (const float*)d_in[33];
  const float* bnw_b = (const float*)d_in[34];

  char* ws = (char*)d_ws;
  const size_t SZBUF = (size_t)51200 * 512 * 2;
  ushort_t* bufA = (ushort_t*)(ws);
  ushort_t* bufB = (ushort_t*)(ws + SZBUF);
  ushort_t* bufC = (ushort_t*)(ws + 2 * SZBUF);
  ushort_t* wfc1 = (ushort_t*)(ws + 3 * SZBUF);
  ushort_t* w2[3];
  w2[0] = wfc1 + 512 * 512;
  w2[1] = w2[0] + 512 * 1024;
  w2[2] = w2[1] + 512 * 1024;
  ushort_t* rwc[8];
  rwc[0] = w2[2] + 512 * 1024;
  for (int i = 1; i < 8; ++i) rwc[i] = rwc[i - 1] + 512 * 512;
  ushort_t* bnfwc = rwc[7] + 512 * 512;
  ushort_t* ws1c  = bnfwc + 128 * 512;
  float* pooled   = (float*)(ws1c + 128 * 128);

  float* out_f = (float*)d_out;
  float* At_f  = out_f + 8192;

  dim3 blk(256);
  // ---- weight/input prep (f32 -> bf16) ----
  {
    long totalx = (long)51200 * 512;
    pad512_f32_kernel<<<dim3((unsigned)((totalx / 4 + 255) / 256)), blk, 0, stream>>>(x, bufA, totalx, 500);
    long totalw = (long)512 * 512;
    pad512_f32_kernel<<<dim3((unsigned)((totalw / 4 + 255) / 256)), blk, 0, stream>>>(fc1_w, wfc1, totalw, 500);
    for (int i = 0; i < 3; ++i)
      repack_tdnn_f32_kernel<<<dim3(2048), blk, 0, stream>>>(tk[i], w2[i]);
    for (int i = 0; i < 4; ++i) {
      cvt_kernel<<<dim3(256), blk, 0, stream>>>(rw1[i], rwc[2 * i], 512 * 512);
      cvt_kernel<<<dim3(256), blk, 0, stream>>>(rw2[i], rwc[2 * i + 1], 512 * 512);
    }
    cvt_kernel<<<dim3(64), blk, 0, stream>>>(bnf_w, bnfwc, 128 * 512);
    cvt_kernel<<<dim3(16), blk, 0, stream>>>(ws1, ws1c, 128 * 128);
  }
  // ---- fc1 (M=51200, K=512pad) ----
  gemm_kernel<512, 1, false><<<dim3(1600), blk, 0, stream>>>(bufA, wfc1, fc1_b, nullptr, nullptr, bufB, 51200, 512, 51200, 51200, 0, 4);
  // ---- res1 ----
  gemm_kernel<512, 1, false><<<dim3(1600), blk, 0, stream>>>(bufB, rwc[0], rb1[0], nullptr, nullptr, bufC, 51200, 512, 51200, 51200, 0, 4);
  gemm_kernel<512, 1, true ><<<dim3(1600), blk, 0, stream>>>(bufC, rwc[1], rb2[0], bufB, rbias[0], bufA, 51200, 512, 51200, 51200, 0, 4);
  // ---- tdnn2 (800 -> 797, sh1=3) ----
  gemm_kernel<1024, 1, false><<<dim3(1596), blk, 0, stream>>>(bufA, w2[0], tb[0], nullptr, nullptr, bufB, 51008, 512, 800, 797, 3, 4);
  // ---- res2 ----
  gemm_kernel<512, 1, false><<<dim3(1596), blk, 0, stream>>>(bufB, rwc[2], rb1[1], nullptr, nullptr, bufC, 51008, 512, 51008, 51008, 0, 4);
  gemm_kernel<512, 1, true ><<<dim3(1596), blk, 0, stream>>>(bufC, rwc[3], rb2[1], bufB, rbias[1], bufA, 51008, 512, 51008, 51008, 0, 4);
  // ---- tdnn3 (797 -> 791, sh1=6) ----
  gemm_kernel<1024, 1, false><<<dim3(1584), blk, 0, stream>>>(bufA, w2[1], tb[1], nullptr, nullptr, bufB, 50624, 512, 797, 791, 6, 4);
  // ---- res3 ----
  gemm_kernel<512, 1, false><<<dim3(1584), blk, 0, stream>>>(bufB, rwc[4], rb1[2], nullptr, nullptr, bufC, 50624, 512, 50624, 50624, 0, 4);
  gemm_kernel<512, 1, true ><<<dim3(1584), blk, 0, stream>>>(bufC, rwc[5], rb2[2], bufB, rbias[2], bufA, 50624, 512, 50624, 50624, 0, 4);
  // ---- tdnn4 (791 -> 782, sh1=9) ----
  gemm_kernel<1024, 1, false><<<dim3(1564), blk, 0, stream>>>(bufA, w2[2], tb[2], nullptr, nullptr, bufB, 50048, 512, 791, 782, 9, 4);
  // ---- res4 ----
  gemm_kernel<512, 1, false><<<dim3(1564), blk, 0, stream>>>(bufB, rwc[6], rb1[3], nullptr, nullptr, bufC, 50048, 512, 50048, 50048, 0, 4);
  gemm_kernel<512, 1, true ><<<dim3(1564), blk, 0, stream>>>(bufC, rwc[7], rb2[3], bufB, rbias[3], bufA, 50048, 512, 50048, 50048, 0, 4);
  // ---- fused bnf + s1 (M = 391*128 = 50048 exactly) ----
  bnf_s1_kernel<<<dim3(391), blk, 0, stream>>>(bufA, bnfwc, bnf_b, ws1c, bufB, bufC);
  // ---- attention softmax -> At (one block per (b,h)) ----
  attn_kernel<<<dim3(320), blk, 0, stream>>>(bufC, ws2, At_f, 782);
  // ---- pooled = At @ hbnf ----
  pool_kernel<<<dim3(64), dim3(640), 0, stream>>>(At_f, bufB, pooled, 782);
  // ---- head ----
  head_kernel<<<dim3(64), dim3(128), 0, stream>>>(pooled, bnw_w, bnw_b, out_f);
}

// Round 11
// 658.566 us; speedup vs baseline: 1.0311x; 1.0311x over previous
//
#include <hip/hip_runtime.h>
#include <hip/hip_bf16.h>

typedef unsigned short ushort_t;
typedef __attribute__((ext_vector_type(8))) short short8;
typedef __attribute__((ext_vector_type(4))) float f32x4;

__device__ __forceinline__ float bf2f(unsigned short u) {
  union { unsigned int i; float f; } v; v.i = ((unsigned int)u) << 16; return v.f;
}
__device__ __forceinline__ unsigned short f2bf(float f) {
  union { float f; unsigned int i; } v; v.f = f;
  unsigned int u = v.i;
  unsigned int r = (u + 0x7fffu + ((u >> 16) & 1u)) >> 16;
  return (unsigned short)r;
}

__device__ __forceinline__ void gload16(const void* g, void* l) {
  __builtin_amdgcn_global_load_lds(
      (const __attribute__((address_space(1))) void*)g,
      (__attribute__((address_space(3))) void*)l, 16, 0, 0);
}

// ============ R3-structure 128x128 kernel, 4 blocks/CU (proven point) ============
// NOTE: (256,5) spills — 60 VGPR + 64 AGPR acc = 124 regs needs the 4-wave/SIMD
// 128-reg budget. R8 measured the spill as +34MB WRITE_SIZE and 1.5x dur.
template<int KTOT, int ACT, bool RES>
__global__ __launch_bounds__(256, 4) void gemm_kernel(
    const ushort_t* __restrict__ A, const ushort_t* __restrict__ W,
    const float* __restrict__ bias,
    const ushort_t* __restrict__ resin, const float* __restrict__ resbias,
    ushort_t* __restrict__ out,
    int M, int Ntot, int T_in, int T_out, int sh1, int ncb)
{
  constexpr int AROW = (KTOT == 1024) ? 512 : KTOT;
  __shared__ ushort_t As[128 * 64];
  __shared__ ushort_t Ws[128 * 64];

  const int tid = threadIdx.x;
  const int lane = tid & 63;
  const int w = tid >> 6;
  const int wm = w >> 1, wn = w & 1;

  // XCD-chunked block swizzle (bijective, m204)
  const int nblocks = (int)gridDim.x;
  const int xcd = blockIdx.x & 7, kk = blockIdx.x >> 3;
  const int q = nblocks >> 3, rr = nblocks & 7;
  const int L = xcd * q + (xcd < rr ? xcd : rr) + kk;
  int rowblk, colblk;
  if (ncb == 4) { rowblk = L >> 2; colblk = L & 3; }
  else          { rowblk = L;      colblk = 0; }
  const int blockN = colblk * 128;
  const int blockRow = rowblk * 128;

  const int b0 = blockRow / T_out;
  const int t0 = blockRow - b0 * T_out;

  f32x4 acc[4][4];
#pragma unroll
  for (int i = 0; i < 4; ++i)
#pragma unroll
    for (int j = 0; j < 4; ++j) acc[i][j] = f32x4{0.f, 0.f, 0.f, 0.f};

  const int mloc = tid >> 3;
  const int csw = (((tid & 7) ^ ((tid >> 3) & 7))) * 8;  // T2 pre-swizzled src chunk

  for (int k0 = 0; k0 < KTOT; k0 += 64) {
    const int kcol = k0 & (AROW - 1);
    const int rowoff = (KTOT == 1024 && k0 >= 512) ? sh1 : 0;
#pragma unroll
    for (int j = 0; j < 4; ++j) {
      int m = j * 32 + mloc;
      int r = blockRow + m;
      int t = t0 + m;
      int bb = b0;
      if (t >= T_out) { ++bb; t -= T_out; }
      long grow = (r < M) ? ((long)bb * T_in + t + rowoff)
                          : ((long)b0 * T_in + t0 + rowoff);
      gload16(A + grow * AROW + kcol + csw, (char*)As + (j * 4096 + tid * 16));
    }
#pragma unroll
    for (int j = 0; j < 4; ++j) {
      int n = blockN + j * 32 + mloc;
      gload16(W + (long)n * KTOT + k0 + csw, (char*)Ws + (j * 4096 + tid * 16));
    }
    __syncthreads();
#pragma unroll
    for (int ks = 0; ks < 64; ks += 32) {
      short8 af[4], bf[4];
      const int hi = lane >> 4;
      const int rlo = lane & 15;
#pragma unroll
      for (int f = 0; f < 4; ++f) {
        int row = wm * 64 + f * 16 + rlo;
        int chunk = (ks >> 3) + hi;
        af[f] = *reinterpret_cast<const short8*>(
            (const char*)As + row * 128 + ((chunk ^ (row & 7)) << 4));
      }
#pragma unroll
      for (int f = 0; f < 4; ++f) {
        int row = wn * 64 + f * 16 + rlo;
        int chunk = (ks >> 3) + hi;
        bf[f] = *reinterpret_cast<const short8*>(
            (const char*)Ws + row * 128 + ((chunk ^ (row & 7)) << 4));
      }
#pragma unroll
      for (int fm = 0; fm < 4; ++fm)
#pragma unroll
        for (int fn = 0; fn < 4; ++fn)
          acc[fm][fn] = __builtin_amdgcn_mfma_f32_16x16x32_bf16(af[fm], bf[fn], acc[fm][fn], 0, 0, 0);
    }
    __syncthreads();
  }

  const int colb = lane & 15;
  const int rowb = (lane >> 4) * 4;
  float bv[4];
#pragma unroll
  for (int fn = 0; fn < 4; ++fn) {
    int col = blockN + wn * 64 + fn * 16 + colb;
    float b = bias ? bias[col] : 0.f;
    if (RES) b += resbias[col];
    bv[fn] = b;
  }
#pragma unroll
  for (int fm = 0; fm < 4; ++fm) {
#pragma unroll
    for (int reg = 0; reg < 4; ++reg) {
      int r = blockRow + wm * 64 + fm * 16 + rowb + reg;
      if (r < M) {
#pragma unroll
        for (int fn = 0; fn < 4; ++fn) {
          int col = blockN + wn * 64 + fn * 16 + colb;
          float v = acc[fm][fn][reg] + bv[fn];
          if (RES) v += bf2f(resin[(long)r * 512 + col]);
          if (ACT == 1) v = fmaxf(v, 0.f);
          else if (ACT == 2) v = tanhf(v);
          out[(long)r * Ntot + col] = f2bf(v);
        }
      }
    }
  }
}

// ============ fused bnf + s1, 64-row tiles (grid 782, 24 KB LDS) ============
// R10 lesson: occupancy was GRID-limited (391 blk x 4 waves = 19% cap).
// 64-row tiles double the grid to 782 (~12 waves/CU).
// Phase 1: H = A @ Wb^T + bb (K=512, N=128). As=smem[0,8K), Ws=smem[8K,24K).
// Phase 2: S = tanh(H @ W1^T). Hs=smem[0,16K) overlays As+Ws (dead after
// phase-1 final barrier); W1 frags read from global (32 KB, L2-resident).
// Waves: wm=w>>1 -> rows wm*32+fm*16 (fm 0..1); wn=w&1 -> cols wn*64+fn*16.
__global__ __launch_bounds__(256, 4) void bnf_s1_kernel(
    const ushort_t* __restrict__ A, const ushort_t* __restrict__ Wb,
    const float* __restrict__ bb, const ushort_t* __restrict__ W1,
    ushort_t* __restrict__ outH, ushort_t* __restrict__ outS)
{
  __shared__ char smem[24576];

  const int tid = threadIdx.x;
  const int lane = tid & 63;
  const int w = tid >> 6;
  const int wm = w >> 1, wn = w & 1;
  const long blockRow = (long)blockIdx.x * 64;

  const int srow = tid >> 3;                        // 0..31
  const int csw = (((tid & 7) ^ (srow & 7))) * 8;   // T2 pre-swizzled src chunk
  const int rlo = lane & 15, hi = lane >> 4;
  const int colb = lane & 15, rowb = (lane >> 4) * 4;

  f32x4 acc[2][4];
#pragma unroll
  for (int i = 0; i < 2; ++i)
#pragma unroll
    for (int j = 0; j < 4; ++j) acc[i][j] = f32x4{0.f, 0.f, 0.f, 0.f};

  // ---- phase 1: bnf GEMM (A-tile 64x64, W-tile 128x64 per K-step) ----
  for (int k0 = 0; k0 < 512; k0 += 64) {
#pragma unroll
    for (int i = 0; i < 2; ++i)
      gload16(A + (blockRow + i * 32 + srow) * 512 + k0 + csw,
              smem + i * 4096 + tid * 16);
#pragma unroll
    for (int j = 0; j < 4; ++j)
      gload16(Wb + (long)(j * 32 + srow) * 512 + k0 + csw,
              smem + 8192 + j * 4096 + tid * 16);
    __syncthreads();
#pragma unroll
    for (int ks = 0; ks < 64; ks += 32) {
      short8 af[2], bf[4];
#pragma unroll
      for (int f = 0; f < 2; ++f) {
        int row = wm * 32 + f * 16 + rlo;            // 0..63
        int chunk = (ks >> 3) + hi;
        af[f] = *reinterpret_cast<const short8*>(
            smem + row * 128 + ((chunk ^ (row & 7)) << 4));
      }
#pragma unroll
      for (int f = 0; f < 4; ++f) {
        int row = wn * 64 + f * 16 + rlo;            // 0..127
        int chunk = (ks >> 3) + hi;
        bf[f] = *reinterpret_cast<const short8*>(
            smem + 8192 + row * 128 + ((chunk ^ (row & 7)) << 4));
      }
#pragma unroll
      for (int fm = 0; fm < 2; ++fm)
#pragma unroll
        for (int fn = 0; fn < 4; ++fn)
          acc[fm][fn] = __builtin_amdgcn_mfma_f32_16x16x32_bf16(af[fm], bf[fn], acc[fm][fn], 0, 0, 0);
    }
    __syncthreads();   // after last iter: As/Ws fully consumed -> Hs may overlay
  }

  // epilogue 1: H -> HBM + Hs (64 rows x 256 B, swizzled, overlaying As/Ws)
#pragma unroll
  for (int fm = 0; fm < 2; ++fm) {
#pragma unroll
    for (int reg = 0; reg < 4; ++reg) {
      int rl = wm * 32 + fm * 16 + rowb + reg;       // 0..63
      long r = blockRow + rl;
#pragma unroll
      for (int fn = 0; fn < 4; ++fn) {
        int col = wn * 64 + fn * 16 + colb;
        float v = acc[fm][fn][reg] + bb[col];
        ushort_t us = f2bf(v);
        outH[r * 128 + col] = us;
        int ch = col >> 3;                           // 16B chunk 0..15
        ((ushort_t*)(smem + rl * 256 + ((ch ^ (rl & 7)) << 4)))[col & 7] = us;
      }
    }
  }
  __syncthreads();

  // ---- phase 2: s1 = tanh(H @ W1^T), K=128; W1 frags straight from global ----
  f32x4 acc2[2][4];
#pragma unroll
  for (int i = 0; i < 2; ++i)
#pragma unroll
    for (int j = 0; j < 4; ++j) acc2[i][j] = f32x4{0.f, 0.f, 0.f, 0.f};
#pragma unroll
  for (int kt = 0; kt < 2; ++kt) {
#pragma unroll
    for (int ks = 0; ks < 64; ks += 32) {
      short8 af[2], bf[4];
#pragma unroll
      for (int f = 0; f < 2; ++f) {
        int row = wm * 32 + f * 16 + rlo;
        int ch = kt * 8 + (ks >> 3) + hi;            // 0..15 within Hs row
        af[f] = *reinterpret_cast<const short8*>(
            smem + row * 256 + ((ch ^ (row & 7)) << 4));
      }
#pragma unroll
      for (int f = 0; f < 4; ++f) {
        int row = wn * 64 + f * 16 + rlo;
        bf[f] = *reinterpret_cast<const short8*>(
            W1 + (long)row * 128 + kt * 64 + ks + hi * 8);
      }
#pragma unroll
      for (int fm = 0; fm < 2; ++fm)
#pragma unroll
        for (int fn = 0; fn < 4; ++fn)
          acc2[fm][fn] = __builtin_amdgcn_mfma_f32_16x16x32_bf16(af[fm], bf[fn], acc2[fm][fn], 0, 0, 0);
    }
  }
#pragma unroll
  for (int fm = 0; fm < 2; ++fm) {
#pragma unroll
    for (int reg = 0; reg < 4; ++reg) {
      long r = blockRow + wm * 32 + fm * 16 + rowb + reg;
#pragma unroll
      for (int fn = 0; fn < 4; ++fn) {
        int col = wn * 64 + fn * 16 + colb;
        outS[r * 128 + col] = f2bf(tanhf(acc2[fm][fn][reg]));
      }
    }
  }
}

__global__ __launch_bounds__(256) void pad512_f32_kernel(
    const float* __restrict__ in, ushort_t* __restrict__ out, long total, int Kin)
{
  long g = ((long)blockIdx.x * 256 + threadIdx.x) * 4;
  if (g >= total) return;
  int r = (int)(g >> 9), c = (int)(g & 511);
  ushort_t o0 = 0, o1 = 0, o2 = 0, o3 = 0;
  if (c < Kin) {
    float4 v = *(const float4*)(in + (long)r * Kin + c);
    o0 = f2bf(v.x); o1 = f2bf(v.y); o2 = f2bf(v.z); o3 = f2bf(v.w);
  }
  unsigned long long pk = (unsigned long long)o0 | ((unsigned long long)o1 << 16) |
                          ((unsigned long long)o2 << 32) | ((unsigned long long)o3 << 48);
  *(unsigned long long*)(out + g) = pk;
}

// 3 TDNN repacks in one launch: which = bid>>11 (2048 blocks each)
// kernel[o,i,s] f32 (strides 1024,2,1) -> W2[o, s*512+i] bf16
__global__ __launch_bounds__(256) void repack3_kernel(
    const float* __restrict__ in0, const float* __restrict__ in1,
    const float* __restrict__ in2, ushort_t* __restrict__ out0,
    ushort_t* __restrict__ out1, ushort_t* __restrict__ out2)
{
  int which = blockIdx.x >> 11;
  int g = (blockIdx.x & 2047) * 256 + threadIdx.x;
  const float* in = (which == 0) ? in0 : (which == 1) ? in1 : in2;
  ushort_t* out = (which == 0) ? out0 : (which == 1) ? out1 : out2;
  int o = g >> 10, rem = g & 1023;
  int s = rem >> 9, i = rem & 511;
  out[g] = f2bf(in[(o << 10) + (i << 1) + s]);
}

// 10 f32->bf16 conversions in one launch. Destinations are CONTIGUOUS in ws
// starting at dst: [8 x 262144 (rwc)] [65536 (bnfw)] [16384 (ws1)].
__global__ __launch_bounds__(256) void multi_cvt_kernel(
    const float* __restrict__ s0, const float* __restrict__ s1,
    const float* __restrict__ s2, const float* __restrict__ s3,
    const float* __restrict__ s4, const float* __restrict__ s5,
    const float* __restrict__ s6, const float* __restrict__ s7,
    const float* __restrict__ s8, const float* __restrict__ s9,
    ushort_t* __restrict__ dst)
{
  long g4 = ((long)blockIdx.x * 256 + threadIdx.x) * 4;
  if (g4 >= 2179072) return;
  const float* src; long off;
  if (g4 < 8L * 262144) {
    int seg = (int)(g4 >> 18); off = g4 & 262143;
    switch (seg) {
      case 0: src = s0; break; case 1: src = s1; break;
      case 2: src = s2; break; case 3: src = s3; break;
      case 4: src = s4; break; case 5: src = s5; break;
      case 6: src = s6; break; default: src = s7; break;
    }
  } else if (g4 < 8L * 262144 + 65536) { src = s8; off = g4 - 8L * 262144; }
  else { src = s9; off = g4 - (8L * 262144 + 65536); }
  float4 v = *(const float4*)(src + off);
  unsigned long long pk = (unsigned long long)f2bf(v.x) | ((unsigned long long)f2bf(v.y) << 16) |
                          ((unsigned long long)f2bf(v.z) << 32) | ((unsigned long long)f2bf(v.w) << 48);
  *(unsigned long long*)(dst + g4) = pk;
}

// one block per (batch, head): scores -> softmax over t -> At (f32)
__global__ __launch_bounds__(256) void attn_kernel(
    const ushort_t* __restrict__ s1, const float* __restrict__ ws2,
    float* __restrict__ At_out, int T)
{
  __shared__ float sc[800];
  __shared__ float w2s[128];
  __shared__ float redm[4], reds[4];
  const int b = blockIdx.x / 5, h = blockIdx.x % 5;
  const int tid = threadIdx.x;
  const int lane = tid & 63, wv = tid >> 6;
  if (tid < 128) w2s[tid] = ws2[h * 128 + tid];
  __syncthreads();
  for (int t = tid; t < T; t += 256) {
    const ushort_t* row = s1 + ((long)b * T + t) * 128;
    float a = 0.f;
    for (int c = 0; c < 128; c += 8) {
      short8 v = *reinterpret_cast<const short8*>(row + c);
#pragma unroll
      for (int j = 0; j < 8; ++j) a += bf2f((unsigned short)v[j]) * w2s[c + j];
    }
    sc[t] = a;
  }
  __syncthreads();
  float m = -1e30f;
  for (int t = tid; t < T; t += 256) m = fmaxf(m, sc[t]);
#pragma unroll
  for (int off = 32; off > 0; off >>= 1) m = fmaxf(m, __shfl_xor(m, off));
  if (lane == 0) redm[wv] = m;
  __syncthreads();
  m = fmaxf(fmaxf(redm[0], redm[1]), fmaxf(redm[2], redm[3]));
  float s = 0.f;
  for (int t = tid; t < T; t += 256) s += expf(sc[t] - m);
#pragma unroll
  for (int off = 32; off > 0; off >>= 1) s += __shfl_xor(s, off);
  if (lane == 0) reds[wv] = s;
  __syncthreads();
  s = reds[0] + reds[1] + reds[2] + reds[3];
  float inv = 1.f / s;
  long base = ((long)b * 5 + h) * T;
  for (int t = tid; t < T; t += 256)
    At_out[base + t] = expf(sc[t] - m) * inv;
}

__global__ __launch_bounds__(640) void pool_kernel(
    const float* __restrict__ At_f, const ushort_t* __restrict__ hb,
    float* __restrict__ pooled, int T)
{
  int b = blockIdx.x, tid = threadIdx.x;
  int h = tid >> 7, d = tid & 127;
  const float* at = At_f + ((long)b * 5 + h) * T;
  const ushort_t* hr = hb + (long)b * T * 128 + d;
  float acc = 0.f;
  int t = 0;
  for (; t + 4 <= T; t += 4) {
    acc += at[t]     * bf2f(hr[(long)(t) * 128]);
    acc += at[t + 1] * bf2f(hr[(long)(t + 1) * 128]);
    acc += at[t + 2] * bf2f(hr[(long)(t + 2) * 128]);
    acc += at[t + 3] * bf2f(hr[(long)(t + 3) * 128]);
  }
  for (; t < T; ++t) acc += at[t] * bf2f(hr[(long)t * 128]);
  pooled[b * 640 + tid] = acc;
}

__global__ __launch_bounds__(128) void head_kernel(
    const float* __restrict__ pooled, const float* __restrict__ w,
    const float* __restrict__ bias, float* __restrict__ out)
{
  int b = blockIdx.x, o = threadIdx.x;
  const float* wr = w + o * 640;
  const float* p = pooled + b * 640;
  float acc = bias[o];
  for (int i = 0; i < 640; i += 4)
    acc += p[i] * wr[i] + p[i + 1] * wr[i + 1] +
           p[i + 2] * wr[i + 2] + p[i + 3] * wr[i + 3];
  out[b * 128 + o] = fmaxf(acc, 0.f);
}

extern "C" void kernel_launch(void* const* d_in, const int* in_sizes, int n_in,
                              void* d_out, int out_size, void* d_ws, size_t ws_size,
                              hipStream_t stream)
{
  (void)in_sizes; (void)n_in; (void)out_size; (void)ws_size;
  const float* x     = (const float*)d_in[0];
  const float* fc1_w = (const float*)d_in[1];
  const float* fc1_b = (const float*)d_in[2];
  const float *rw1[4], *rb1[4], *rw2[4], *rb2[4], *rbias[4];
  for (int i = 0; i < 4; ++i) {
    rw1[i]   = (const float*)d_in[3 + 5 * i + 0];
    rb1[i]   = (const float*)d_in[3 + 5 * i + 1];
    rw2[i]   = (const float*)d_in[3 + 5 * i + 2];
    rb2[i]   = (const float*)d_in[3 + 5 * i + 3];
    rbias[i] = (const float*)d_in[3 + 5 * i + 4];
  }
  const float *tk[3], *tb[3];
  for (int i = 0; i < 3; ++i) {
    tk[i] = (const float*)d_in[23 + 2 * i];
    tb[i] = (const float*)d_in[24 + 2 * i];
  }
  const float* bnf_w = (const float*)d_in[29];
  const float* bnf_b = (const float*)d_in[30];
  const float* ws1   = (const float*)d_in[31];
  const float* ws2   = (const float*)d_in[32];
  const float* bnw_w = (const float*)d_in[33];
  const float* bnw_b = (const float*)d_in[34];

  char* ws = (char*)d_ws;
  const size_t SZBUF = (size_t)51200 * 512 * 2;
  ushort_t* bufA = (ushort_t*)(ws);
  ushort_t* bufB = (ushort_t*)(ws + SZBUF);
  ushort_t* bufC = (ushort_t*)(ws + 2 * SZBUF);
  ushort_t* wfc1 = (ushort_t*)(ws + 3 * SZBUF);
  ushort_t* w2[3];
  w2[0] = wfc1 + 512 * 512;
  w2[1] = w2[0] + 512 * 1024;
  w2[2] = w2[1] + 512 * 1024;
  ushort_t* rwc[8];
  rwc[0] = w2[2] + 512 * 1024;
  for (int i = 1; i < 8; ++i) rwc[i] = rwc[i - 1] + 512 * 512;
  ushort_t* bnfwc = rwc[7] + 512 * 512;
  ushort_t* ws1c  = bnfwc + 128 * 512;
  float* pooled   = (float*)(ws1c + 128 * 128);

  float* out_f = (float*)d_out;
  float* At_f  = out_f + 8192;

  dim3 blk(256);
  // ---- weight/input prep (f32 -> bf16), 4 launches ----
  {
    long totalx = (long)51200 * 512;
    pad512_f32_kernel<<<dim3((unsigned)((totalx / 4 + 255) / 256)), blk, 0, stream>>>(x, bufA, totalx, 500);
    long totalw = (long)512 * 512;
    pad512_f32_kernel<<<dim3((unsigned)((totalw / 4 + 255) / 256)), blk, 0, stream>>>(fc1_w, wfc1, totalw, 500);
    repack3_kernel<<<dim3(6144), blk, 0, stream>>>(tk[0], tk[1], tk[2], w2[0], w2[1], w2[2]);
    multi_cvt_kernel<<<dim3(2128), blk, 0, stream>>>(
        rw1[0], rw2[0], rw1[1], rw2[1], rw1[2], rw2[2], rw1[3], rw2[3],
        bnf_w, ws1, rwc[0]);
  }
  // ---- fc1 (M=51200, K=512pad) ----
  gemm_kernel<512, 1, false><<<dim3(1600), blk, 0, stream>>>(bufA, wfc1, fc1_b, nullptr, nullptr, bufB, 51200, 512, 51200, 51200, 0, 4);
  // ---- res1 ----
  gemm_kernel<512, 1, false><<<dim3(1600), blk, 0, stream>>>(bufB, rwc[0], rb1[0], nullptr, nullptr, bufC, 51200, 512, 51200, 51200, 0, 4);
  gemm_kernel<512, 1, true ><<<dim3(1600), blk, 0, stream>>>(bufC, rwc[1], rb2[0], bufB, rbias[0], bufA, 51200, 512, 51200, 51200, 0, 4);
  // ---- tdnn2 (800 -> 797, sh1=3) ----
  gemm_kernel<1024, 1, false><<<dim3(1596), blk, 0, stream>>>(bufA, w2[0], tb[0], nullptr, nullptr, bufB, 51008, 512, 800, 797, 3, 4);
  // ---- res2 ----
  gemm_kernel<512, 1, false><<<dim3(1596), blk, 0, stream>>>(bufB, rwc[2], rb1[1], nullptr, nullptr, bufC, 51008, 512, 51008, 51008, 0, 4);
  gemm_kernel<512, 1, true ><<<dim3(1596), blk, 0, stream>>>(bufC, rwc[3], rb2[1], bufB, rbias[1], bufA, 51008, 512, 51008, 51008, 0, 4);
  // ---- tdnn3 (797 -> 791, sh1=6) ----
  gemm_kernel<1024, 1, false><<<dim3(1584), blk, 0, stream>>>(bufA, w2[1], tb[1], nullptr, nullptr, bufB, 50624, 512, 797, 791, 6, 4);
  // ---- res3 ----
  gemm_kernel<512, 1, false><<<dim3(1584), blk, 0, stream>>>(bufB, rwc[4], rb1[2], nullptr, nullptr, bufC, 50624, 512, 50624, 50624, 0, 4);
  gemm_kernel<512, 1, true ><<<dim3(1584), blk, 0, stream>>>(bufC, rwc[5], rb2[2], bufB, rbias[2], bufA, 50624, 512, 50624, 50624, 0, 4);
  // ---- tdnn4 (791 -> 782, sh1=9) ----
  gemm_kernel<1024, 1, false><<<dim3(1564), blk, 0, stream>>>(bufA, w2[2], tb[2], nullptr, nullptr, bufB, 50048, 512, 791, 782, 9, 4);
  // ---- res4 ----
  gemm_kernel<512, 1, false><<<dim3(1564), blk, 0, stream>>>(bufB, rwc[6], rb1[3], nullptr, nullptr, bufC, 50048, 512, 50048, 50048, 0, 4);
  gemm_kernel<512, 1, true ><<<dim3(1564), blk, 0, stream>>>(bufC, rwc[7], rb2[3], bufB, rbias[3], bufA, 50048, 512, 50048, 50048, 0, 4);
  // ---- fused bnf + s1 (64-row tiles: 50048/64 = 782 blocks) ----
  bnf_s1_kernel<<<dim3(782), blk, 0, stream>>>(bufA, bnfwc, bnf_b, ws1c, bufB, bufC);
  // ---- attention softmax -> At (one block per (b,h)) ----
  attn_kernel<<<dim3(320), blk, 0, stream>>>(bufC, ws2, At_f, 782);
  // ---- pooled = At @ hbnf ----
  pool_kernel<<<dim3(64), dim3(640), 0, stream>>>(At_f, bufB, pooled, 782);
  // ---- head ----
  head_kernel<<<dim3(64), dim3(128), 0, stream>>>(pooled, bnw_w, bnw_b, out_f);
}

// Round 12
// 623.206 us; speedup vs baseline: 1.0896x; 1.0567x over previous
//
#include <hip/hip_runtime.h>
#include <hip/hip_bf16.h>

typedef unsigned short ushort_t;
typedef __attribute__((ext_vector_type(8))) short short8;
typedef __attribute__((ext_vector_type(4))) float f32x4;

__device__ __forceinline__ float bf2f(unsigned short u) {
  union { unsigned int i; float f; } v; v.i = ((unsigned int)u) << 16; return v.f;
}
__device__ __forceinline__ unsigned short f2bf(float f) {
  union { float f; unsigned int i; } v; v.f = f;
  unsigned int u = v.i;
  unsigned int r = (u + 0x7fffu + ((u >> 16) & 1u)) >> 16;
  return (unsigned short)r;
}

__device__ __forceinline__ void gload16(const void* g, void* l) {
  __builtin_amdgcn_global_load_lds(
      (const __attribute__((address_space(1))) void*)g,
      (__attribute__((address_space(3))) void*)l, 16, 0, 0);
}

// ============ R3-structure 128x128 kernel, 4 blocks/CU (proven point) ============
// NOTE: (256,5) spills — 60 VGPR + 64 acc = 124 regs needs the 4-wave/SIMD
// 128-reg budget (R8: spill = +34MB WRITE_SIZE, 1.5x dur). Do NOT add state.
template<int KTOT, int ACT, bool RES>
__global__ __launch_bounds__(256, 4) void gemm_kernel(
    const ushort_t* __restrict__ A, const ushort_t* __restrict__ W,
    const float* __restrict__ bias,
    const ushort_t* __restrict__ resin, const float* __restrict__ resbias,
    ushort_t* __restrict__ out,
    int M, int Ntot, int T_in, int T_out, int sh1, int ncb)
{
  constexpr int AROW = (KTOT == 1024) ? 512 : KTOT;
  __shared__ ushort_t As[128 * 64];
  __shared__ ushort_t Ws[128 * 64];

  const int tid = threadIdx.x;
  const int lane = tid & 63;
  const int w = tid >> 6;
  const int wm = w >> 1, wn = w & 1;

  // XCD-chunked block swizzle (bijective, m204)
  const int nblocks = (int)gridDim.x;
  const int xcd = blockIdx.x & 7, kk = blockIdx.x >> 3;
  const int q = nblocks >> 3, rr = nblocks & 7;
  const int L = xcd * q + (xcd < rr ? xcd : rr) + kk;
  int rowblk, colblk;
  if (ncb == 4) { rowblk = L >> 2; colblk = L & 3; }
  else          { rowblk = L;      colblk = 0; }
  const int blockN = colblk * 128;
  const int blockRow = rowblk * 128;

  const int b0 = blockRow / T_out;
  const int t0 = blockRow - b0 * T_out;

  f32x4 acc[4][4];
#pragma unroll
  for (int i = 0; i < 4; ++i)
#pragma unroll
    for (int j = 0; j < 4; ++j) acc[i][j] = f32x4{0.f, 0.f, 0.f, 0.f};

  const int mloc = tid >> 3;
  const int csw = (((tid & 7) ^ ((tid >> 3) & 7))) * 8;  // T2 pre-swizzled src chunk

  for (int k0 = 0; k0 < KTOT; k0 += 64) {
    const int kcol = k0 & (AROW - 1);
    const int rowoff = (KTOT == 1024 && k0 >= 512) ? sh1 : 0;
#pragma unroll
    for (int j = 0; j < 4; ++j) {
      int m = j * 32 + mloc;
      int r = blockRow + m;
      int t = t0 + m;
      int bb = b0;
      if (t >= T_out) { ++bb; t -= T_out; }
      long grow = (r < M) ? ((long)bb * T_in + t + rowoff)
                          : ((long)b0 * T_in + t0 + rowoff);
      gload16(A + grow * AROW + kcol + csw, (char*)As + (j * 4096 + tid * 16));
    }
#pragma unroll
    for (int j = 0; j < 4; ++j) {
      int n = blockN + j * 32 + mloc;
      gload16(W + (long)n * KTOT + k0 + csw, (char*)Ws + (j * 4096 + tid * 16));
    }
    __syncthreads();
#pragma unroll
    for (int ks = 0; ks < 64; ks += 32) {
      short8 af[4], bf[4];
      const int hi = lane >> 4;
      const int rlo = lane & 15;
#pragma unroll
      for (int f = 0; f < 4; ++f) {
        int row = wm * 64 + f * 16 + rlo;
        int chunk = (ks >> 3) + hi;
        af[f] = *reinterpret_cast<const short8*>(
            (const char*)As + row * 128 + ((chunk ^ (row & 7)) << 4));
      }
#pragma unroll
      for (int f = 0; f < 4; ++f) {
        int row = wn * 64 + f * 16 + rlo;
        int chunk = (ks >> 3) + hi;
        bf[f] = *reinterpret_cast<const short8*>(
            (const char*)Ws + row * 128 + ((chunk ^ (row & 7)) << 4));
      }
#pragma unroll
      for (int fm = 0; fm < 4; ++fm)
#pragma unroll
        for (int fn = 0; fn < 4; ++fn)
          acc[fm][fn] = __builtin_amdgcn_mfma_f32_16x16x32_bf16(af[fm], bf[fn], acc[fm][fn], 0, 0, 0);
    }
    __syncthreads();
  }

  const int colb = lane & 15;
  const int rowb = (lane >> 4) * 4;
  float bv[4];
#pragma unroll
  for (int fn = 0; fn < 4; ++fn) {
    int col = blockN + wn * 64 + fn * 16 + colb;
    float b = bias ? bias[col] : 0.f;
    if (RES) b += resbias[col];
    bv[fn] = b;
  }
#pragma unroll
  for (int fm = 0; fm < 4; ++fm) {
#pragma unroll
    for (int reg = 0; reg < 4; ++reg) {
      int r = blockRow + wm * 64 + fm * 16 + rowb + reg;
      if (r < M) {
#pragma unroll
        for (int fn = 0; fn < 4; ++fn) {
          int col = blockN + wn * 64 + fn * 16 + colb;
          float v = acc[fm][fn][reg] + bv[fn];
          if (RES) v += bf2f(resin[(long)r * 512 + col]);
          if (ACT == 1) v = fmaxf(v, 0.f);
          else if (ACT == 2) v = tanhf(v);
          out[(long)r * Ntot + col] = f2bf(v);
        }
      }
    }
  }
}

// ============ fused bnf + s1, 64-row tiles (grid 782, 24 KB LDS) ============
__global__ __launch_bounds__(256, 4) void bnf_s1_kernel(
    const ushort_t* __restrict__ A, const ushort_t* __restrict__ Wb,
    const float* __restrict__ bb, const ushort_t* __restrict__ W1,
    ushort_t* __restrict__ outH, ushort_t* __restrict__ outS)
{
  __shared__ char smem[24576];

  const int tid = threadIdx.x;
  const int lane = tid & 63;
  const int w = tid >> 6;
  const int wm = w >> 1, wn = w & 1;
  const long blockRow = (long)blockIdx.x * 64;

  const int srow = tid >> 3;                        // 0..31
  const int csw = (((tid & 7) ^ (srow & 7))) * 8;   // T2 pre-swizzled src chunk
  const int rlo = lane & 15, hi = lane >> 4;
  const int colb = lane & 15, rowb = (lane >> 4) * 4;

  f32x4 acc[2][4];
#pragma unroll
  for (int i = 0; i < 2; ++i)
#pragma unroll
    for (int j = 0; j < 4; ++j) acc[i][j] = f32x4{0.f, 0.f, 0.f, 0.f};

  // ---- phase 1: bnf GEMM (A-tile 64x64, W-tile 128x64 per K-step) ----
  for (int k0 = 0; k0 < 512; k0 += 64) {
#pragma unroll
    for (int i = 0; i < 2; ++i)
      gload16(A + (blockRow + i * 32 + srow) * 512 + k0 + csw,
              smem + i * 4096 + tid * 16);
#pragma unroll
    for (int j = 0; j < 4; ++j)
      gload16(Wb + (long)(j * 32 + srow) * 512 + k0 + csw,
              smem + 8192 + j * 4096 + tid * 16);
    __syncthreads();
#pragma unroll
    for (int ks = 0; ks < 64; ks += 32) {
      short8 af[2], bf[4];
#pragma unroll
      for (int f = 0; f < 2; ++f) {
        int row = wm * 32 + f * 16 + rlo;
        int chunk = (ks >> 3) + hi;
        af[f] = *reinterpret_cast<const short8*>(
            smem + row * 128 + ((chunk ^ (row & 7)) << 4));
      }
#pragma unroll
      for (int f = 0; f < 4; ++f) {
        int row = wn * 64 + f * 16 + rlo;
        int chunk = (ks >> 3) + hi;
        bf[f] = *reinterpret_cast<const short8*>(
            smem + 8192 + row * 128 + ((chunk ^ (row & 7)) << 4));
      }
#pragma unroll
      for (int fm = 0; fm < 2; ++fm)
#pragma unroll
        for (int fn = 0; fn < 4; ++fn)
          acc[fm][fn] = __builtin_amdgcn_mfma_f32_16x16x32_bf16(af[fm], bf[fn], acc[fm][fn], 0, 0, 0);
    }
    __syncthreads();
  }

  // epilogue 1: H -> HBM + Hs (64 rows x 256 B, swizzled, overlaying As/Ws)
#pragma unroll
  for (int fm = 0; fm < 2; ++fm) {
#pragma unroll
    for (int reg = 0; reg < 4; ++reg) {
      int rl = wm * 32 + fm * 16 + rowb + reg;
      long r = blockRow + rl;
#pragma unroll
      for (int fn = 0; fn < 4; ++fn) {
        int col = wn * 64 + fn * 16 + colb;
        float v = acc[fm][fn][reg] + bb[col];
        ushort_t us = f2bf(v);
        outH[r * 128 + col] = us;
        int ch = col >> 3;
        ((ushort_t*)(smem + rl * 256 + ((ch ^ (rl & 7)) << 4)))[col & 7] = us;
      }
    }
  }
  __syncthreads();

  // ---- phase 2: s1 = tanh(H @ W1^T), K=128; W1 frags straight from global ----
  f32x4 acc2[2][4];
#pragma unroll
  for (int i = 0; i < 2; ++i)
#pragma unroll
    for (int j = 0; j < 4; ++j) acc2[i][j] = f32x4{0.f, 0.f, 0.f, 0.f};
#pragma unroll
  for (int kt = 0; kt < 2; ++kt) {
#pragma unroll
    for (int ks = 0; ks < 64; ks += 32) {
      short8 af[2], bf[4];
#pragma unroll
      for (int f = 0; f < 2; ++f) {
        int row = wm * 32 + f * 16 + rlo;
        int ch = kt * 8 + (ks >> 3) + hi;
        af[f] = *reinterpret_cast<const short8*>(
            smem + row * 256 + ((ch ^ (row & 7)) << 4));
      }
#pragma unroll
      for (int f = 0; f < 4; ++f) {
        int row = wn * 64 + f * 16 + rlo;
        bf[f] = *reinterpret_cast<const short8*>(
            W1 + (long)row * 128 + kt * 64 + ks + hi * 8);
      }
#pragma unroll
      for (int fm = 0; fm < 2; ++fm)
#pragma unroll
        for (int fn = 0; fn < 4; ++fn)
          acc2[fm][fn] = __builtin_amdgcn_mfma_f32_16x16x32_bf16(af[fm], bf[fn], acc2[fm][fn], 0, 0, 0);
    }
  }
#pragma unroll
  for (int fm = 0; fm < 2; ++fm) {
#pragma unroll
    for (int reg = 0; reg < 4; ++reg) {
      long r = blockRow + wm * 32 + fm * 16 + rowb + reg;
#pragma unroll
      for (int fn = 0; fn < 4; ++fn) {
        int col = wn * 64 + fn * 16 + colb;
        outS[r * 128 + col] = f2bf(tanhf(acc2[fm][fn][reg]));
      }
    }
  }
}

__global__ __launch_bounds__(256) void pad512_f32_kernel(
    const float* __restrict__ in, ushort_t* __restrict__ out, long total, int Kin)
{
  long g = ((long)blockIdx.x * 256 + threadIdx.x) * 4;
  if (g >= total) return;
  int r = (int)(g >> 9), c = (int)(g & 511);
  ushort_t o0 = 0, o1 = 0, o2 = 0, o3 = 0;
  if (c < Kin) {
    float4 v = *(const float4*)(in + (long)r * Kin + c);
    o0 = f2bf(v.x); o1 = f2bf(v.y); o2 = f2bf(v.z); o3 = f2bf(v.w);
  }
  unsigned long long pk = (unsigned long long)o0 | ((unsigned long long)o1 << 16) |
                          ((unsigned long long)o2 << 32) | ((unsigned long long)o3 << 48);
  *(unsigned long long*)(out + g) = pk;
}

// 3 TDNN repacks in one launch: which = bid>>11 (2048 blocks each)
__global__ __launch_bounds__(256) void repack3_kernel(
    const float* __restrict__ in0, const float* __restrict__ in1,
    const float* __restrict__ in2, ushort_t* __restrict__ out0,
    ushort_t* __restrict__ out1, ushort_t* __restrict__ out2)
{
  int which = blockIdx.x >> 11;
  int g = (blockIdx.x & 2047) * 256 + threadIdx.x;
  const float* in = (which == 0) ? in0 : (which == 1) ? in1 : in2;
  ushort_t* out = (which == 0) ? out0 : (which == 1) ? out1 : out2;
  int o = g >> 10, rem = g & 1023;
  int s = rem >> 9, i = rem & 511;
  out[g] = f2bf(in[(o << 10) + (i << 1) + s]);
}

// 10 f32->bf16 conversions in one launch; destinations contiguous in ws.
__global__ __launch_bounds__(256) void multi_cvt_kernel(
    const float* __restrict__ s0, const float* __restrict__ s1,
    const float* __restrict__ s2, const float* __restrict__ s3,
    const float* __restrict__ s4, const float* __restrict__ s5,
    const float* __restrict__ s6, const float* __restrict__ s7,
    const float* __restrict__ s8, const float* __restrict__ s9,
    ushort_t* __restrict__ dst)
{
  long g4 = ((long)blockIdx.x * 256 + threadIdx.x) * 4;
  if (g4 >= 2179072) return;
  const float* src; long off;
  if (g4 < 8L * 262144) {
    int seg = (int)(g4 >> 18); off = g4 & 262143;
    switch (seg) {
      case 0: src = s0; break; case 1: src = s1; break;
      case 2: src = s2; break; case 3: src = s3; break;
      case 4: src = s4; break; case 5: src = s5; break;
      case 6: src = s6; break; default: src = s7; break;
    }
  } else if (g4 < 8L * 262144 + 65536) { src = s8; off = g4 - 8L * 262144; }
  else { src = s9; off = g4 - (8L * 262144 + 65536); }
  float4 v = *(const float4*)(src + off);
  unsigned long long pk = (unsigned long long)f2bf(v.x) | ((unsigned long long)f2bf(v.y) << 16) |
                          ((unsigned long long)f2bf(v.z) << 32) | ((unsigned long long)f2bf(v.w) << 48);
  *(unsigned long long*)(dst + g4) = pk;
}

// one block per (batch, head): scores -> softmax over t -> At (f32)
__global__ __launch_bounds__(256) void attn_kernel(
    const ushort_t* __restrict__ s1, const float* __restrict__ ws2,
    float* __restrict__ At_out, int T)
{
  __shared__ float sc[800];
  __shared__ float w2s[128];
  __shared__ float redm[4], reds[4];
  const int b = blockIdx.x / 5, h = blockIdx.x % 5;
  const int tid = threadIdx.x;
  const int lane = tid & 63, wv = tid >> 6;
  if (tid < 128) w2s[tid] = ws2[h * 128 + tid];
  __syncthreads();
  for (int t = tid; t < T; t += 256) {
    const ushort_t* row = s1 + ((long)b * T + t) * 128;
    float a = 0.f;
    for (int c = 0; c < 128; c += 8) {
      short8 v = *reinterpret_cast<const short8*>(row + c);
#pragma unroll
      for (int j = 0; j < 8; ++j) a += bf2f((unsigned short)v[j]) * w2s[c + j];
    }
    sc[t] = a;
  }
  __syncthreads();
  float m = -1e30f;
  for (int t = tid; t < T; t += 256) m = fmaxf(m, sc[t]);
#pragma unroll
  for (int off = 32; off > 0; off >>= 1) m = fmaxf(m, __shfl_xor(m, off));
  if (lane == 0) redm[wv] = m;
  __syncthreads();
  m = fmaxf(fmaxf(redm[0], redm[1]), fmaxf(redm[2], redm[3]));
  float s = 0.f;
  for (int t = tid; t < T; t += 256) s += expf(sc[t] - m);
#pragma unroll
  for (int off = 32; off > 0; off >>= 1) s += __shfl_xor(s, off);
  if (lane == 0) reds[wv] = s;
  __syncthreads();
  s = reds[0] + reds[1] + reds[2] + reds[3];
  float inv = 1.f / s;
  long base = ((long)b * 5 + h) * T;
  for (int t = tid; t < T; t += 256)
    At_out[base + t] = expf(sc[t] - m) * inv;
}

// ---- pool stage 1: partial[c][b][tid] = sum_{t in chunk c} At[b,h,t]*hb[b,t,d]
// grid = NC*64 blocks (c = bid>>6, b = bid&63), 640 thr (h = tid>>7, d = tid&127).
// R11 lesson: the old 64-block pool was latency-bound at 0.25 blocks/CU.
__global__ __launch_bounds__(640) void pool_partial_kernel(
    const float* __restrict__ At_f, const ushort_t* __restrict__ hb,
    float* __restrict__ part, int T)
{
  int c = blockIdx.x >> 6;
  int b = blockIdx.x & 63;
  int tid = threadIdx.x;
  int h = tid >> 7, d = tid & 127;
  int t0 = c * 64;
  int t1 = t0 + 64; if (t1 > T) t1 = T;
  const float* at = At_f + ((long)b * 5 + h) * T;
  const ushort_t* hr = hb + (long)b * T * 128 + d;
  float acc = 0.f;
  int t = t0;
  for (; t + 4 <= t1; t += 4) {
    acc += at[t]     * bf2f(hr[(long)(t) * 128]);
    acc += at[t + 1] * bf2f(hr[(long)(t + 1) * 128]);
    acc += at[t + 2] * bf2f(hr[(long)(t + 2) * 128]);
    acc += at[t + 3] * bf2f(hr[(long)(t + 3) * 128]);
  }
  for (; t < t1; ++t) acc += at[t] * bf2f(hr[(long)t * 128]);
  part[((long)c * 64 + b) * 640 + tid] = acc;
}

// ---- pool stage 2: fixed-order deterministic reduce over NC chunks ----
__global__ __launch_bounds__(640) void pool_reduce_kernel(
    const float* __restrict__ part, float* __restrict__ pooled, int nc)
{
  int b = blockIdx.x, tid = threadIdx.x;
  float s = 0.f;
  for (int c = 0; c < nc; ++c) s += part[((long)c * 64 + b) * 640 + tid];
  pooled[b * 640 + tid] = s;
}

// out[b,o] = relu( pooled[b,:].bnw_w[o,:] + bnw_b[o] ); 4 lanes per o.
__global__ __launch_bounds__(512) void head_kernel(
    const float* __restrict__ pooled, const float* __restrict__ w,
    const float* __restrict__ bias, float* __restrict__ out)
{
  int b = blockIdx.x;
  int o = threadIdx.x >> 2;
  int part = threadIdx.x & 3;
  const float* wr = w + o * 640 + part * 160;
  const float* p = pooled + b * 640 + part * 160;
  float acc = 0.f;
#pragma unroll 4
  for (int i = 0; i < 160; i += 4)
    acc += p[i] * wr[i] + p[i + 1] * wr[i + 1] +
           p[i + 2] * wr[i + 2] + p[i + 3] * wr[i + 3];
  acc += __shfl_xor(acc, 1);   // lanes 4o..4o+3 are adjacent within one wave
  acc += __shfl_xor(acc, 2);
  if (part == 0) out[b * 128 + o] = fmaxf(acc + bias[o], 0.f);
}

extern "C" void kernel_launch(void* const* d_in, const int* in_sizes, int n_in,
                              void* d_out, int out_size, void* d_ws, size_t ws_size,
                              hipStream_t stream)
{
  (void)in_sizes; (void)n_in; (void)out_size; (void)ws_size;
  const float* x     = (const float*)d_in[0];
  const float* fc1_w = (const float*)d_in[1];
  const float* fc1_b = (const float*)d_in[2];
  const float *rw1[4], *rb1[4], *rw2[4], *rb2[4], *rbias[4];
  for (int i = 0; i < 4; ++i) {
    rw1[i]   = (const float*)d_in[3 + 5 * i + 0];
    rb1[i]   = (const float*)d_in[3 + 5 * i + 1];
    rw2[i]   = (const float*)d_in[3 + 5 * i + 2];
    rb2[i]   = (const float*)d_in[3 + 5 * i + 3];
    rbias[i] = (const float*)d_in[3 + 5 * i + 4];
  }
  const float *tk[3], *tb[3];
  for (int i = 0; i < 3; ++i) {
    tk[i] = (const float*)d_in[23 + 2 * i];
    tb[i] = (const float*)d_in[24 + 2 * i];
  }
  const float* bnf_w = (const float*)d_in[29];
  const float* bnf_b = (const float*)d_in[30];
  const float* ws1   = (const float*)d_in[31];
  const float* ws2   = (const float*)d_in[32];
  const float* bnw_w = (const float*)d_in[33];
  const float* bnw_b = (const float*)d_in[34];

  char* ws = (char*)d_ws;
  const size_t SZBUF = (size_t)51200 * 512 * 2;
  ushort_t* bufA = (ushort_t*)(ws);
  ushort_t* bufB = (ushort_t*)(ws + SZBUF);
  ushort_t* bufC = (ushort_t*)(ws + 2 * SZBUF);
  ushort_t* wfc1 = (ushort_t*)(ws + 3 * SZBUF);
  ushort_t* w2[3];
  w2[0] = wfc1 + 512 * 512;
  w2[1] = w2[0] + 512 * 1024;
  w2[2] = w2[1] + 512 * 1024;
  ushort_t* rwc[8];
  rwc[0] = w2[2] + 512 * 1024;
  for (int i = 1; i < 8; ++i) rwc[i] = rwc[i - 1] + 512 * 512;
  ushort_t* bnfwc = rwc[7] + 512 * 512;
  ushort_t* ws1c  = bnfwc + 128 * 512;
  float* pooled   = (float*)(ws1c + 128 * 128);
  float* part     = pooled + 64 * 640;         // [13][64][640] f32

  float* out_f = (float*)d_out;
  float* At_f  = out_f + 8192;

  dim3 blk(256);
  // ---- weight/input prep (f32 -> bf16), 4 launches ----
  {
    long totalx = (long)51200 * 512;
    pad512_f32_kernel<<<dim3((unsigned)((totalx / 4 + 255) / 256)), blk, 0, stream>>>(x, bufA, totalx, 500);
    long totalw = (long)512 * 512;
    pad512_f32_kernel<<<dim3((unsigned)((totalw / 4 + 255) / 256)), blk, 0, stream>>>(fc1_w, wfc1, totalw, 500);
    repack3_kernel<<<dim3(6144), blk, 0, stream>>>(tk[0], tk[1], tk[2], w2[0], w2[1], w2[2]);
    multi_cvt_kernel<<<dim3(2128), blk, 0, stream>>>(
        rw1[0], rw2[0], rw1[1], rw2[1], rw1[2], rw2[2], rw1[3], rw2[3],
        bnf_w, ws1, rwc[0]);
  }
  // ---- fc1 (M=51200, K=512pad) ----
  gemm_kernel<512, 1, false><<<dim3(1600), blk, 0, stream>>>(bufA, wfc1, fc1_b, nullptr, nullptr, bufB, 51200, 512, 51200, 51200, 0, 4);
  // ---- res1 ----
  gemm_kernel<512, 1, false><<<dim3(1600), blk, 0, stream>>>(bufB, rwc[0], rb1[0], nullptr, nullptr, bufC, 51200, 512, 51200, 51200, 0, 4);
  gemm_kernel<512, 1, true ><<<dim3(1600), blk, 0, stream>>>(bufC, rwc[1], rb2[0], bufB, rbias[0], bufA, 51200, 512, 51200, 51200, 0, 4);
  // ---- tdnn2 (800 -> 797, sh1=3) ----
  gemm_kernel<1024, 1, false><<<dim3(1596), blk, 0, stream>>>(bufA, w2[0], tb[0], nullptr, nullptr, bufB, 51008, 512, 800, 797, 3, 4);
  // ---- res2 ----
  gemm_kernel<512, 1, false><<<dim3(1596), blk, 0, stream>>>(bufB, rwc[2], rb1[1], nullptr, nullptr, bufC, 51008, 512, 51008, 51008, 0, 4);
  gemm_kernel<512, 1, true ><<<dim3(1596), blk, 0, stream>>>(bufC, rwc[3], rb2[1], bufB, rbias[1], bufA, 51008, 512, 51008, 51008, 0, 4);
  // ---- tdnn3 (797 -> 791, sh1=6) ----
  gemm_kernel<1024, 1, false><<<dim3(1584), blk, 0, stream>>>(bufA, w2[1], tb[1], nullptr, nullptr, bufB, 50624, 512, 797, 791, 6, 4);
  // ---- res3 ----
  gemm_kernel<512, 1, false><<<dim3(1584), blk, 0, stream>>>(bufB, rwc[4], rb1[2], nullptr, nullptr, bufC, 50624, 512, 50624, 50624, 0, 4);
  gemm_kernel<512, 1, true ><<<dim3(1584), blk, 0, stream>>>(bufC, rwc[5], rb2[2], bufB, rbias[2], bufA, 50624, 512, 50624, 50624, 0, 4);
  // ---- tdnn4 (791 -> 782, sh1=9) ----
  gemm_kernel<1024, 1, false><<<dim3(1564), blk, 0, stream>>>(bufA, w2[2], tb[2], nullptr, nullptr, bufB, 50048, 512, 791, 782, 9, 4);
  // ---- res4 ----
  gemm_kernel<512, 1, false><<<dim3(1564), blk, 0, stream>>>(bufB, rwc[6], rb1[3], nullptr, nullptr, bufC, 50048, 512, 50048, 50048, 0, 4);
  gemm_kernel<512, 1, true ><<<dim3(1564), blk, 0, stream>>>(bufC, rwc[7], rb2[3], bufB, rbias[3], bufA, 50048, 512, 50048, 50048, 0, 4);
  // ---- fused bnf + s1 (64-row tiles: 50048/64 = 782 blocks) ----
  bnf_s1_kernel<<<dim3(782), blk, 0, stream>>>(bufA, bnfwc, bnf_b, ws1c, bufB, bufC);
  // ---- attention softmax -> At (one block per (b,h)) ----
  attn_kernel<<<dim3(320), blk, 0, stream>>>(bufC, ws2, At_f, 782);
  // ---- pooled = At @ hbnf, two-stage (13 chunks of 64 t) ----
  pool_partial_kernel<<<dim3(13 * 64), dim3(640), 0, stream>>>(At_f, bufB, part, 782);
  pool_reduce_kernel<<<dim3(64), dim3(640), 0, stream>>>(part, pooled, 13);
  // ---- head ----
  head_kernel<<<dim3(64), dim3(512), 0, stream>>>(pooled, bnw_w, bnw_b, out_f);
}

// Round 13
// 623.066 us; speedup vs baseline: 1.0898x; 1.0002x over previous
//
#include <hip/hip_runtime.h>
#include <hip/hip_bf16.h>

typedef unsigned short ushort_t;
typedef __attribute__((ext_vector_type(8))) short short8;
typedef __attribute__((ext_vector_type(4))) float f32x4;

__device__ __forceinline__ float bf2f(unsigned short u) {
  union { unsigned int i; float f; } v; v.i = ((unsigned int)u) << 16; return v.f;
}
__device__ __forceinline__ unsigned short f2bf(float f) {
  union { float f; unsigned int i; } v; v.f = f;
  unsigned int u = v.i;
  unsigned int r = (u + 0x7fffu + ((u >> 16) & 1u)) >> 16;
  return (unsigned short)r;
}

__device__ __forceinline__ void gload16(const void* g, void* l) {
  __builtin_amdgcn_global_load_lds(
      (const __attribute__((address_space(1))) void*)g,
      (__attribute__((address_space(3))) void*)l, 16, 0, 0);
}

// ============ R3-structure 128x128 kernel, 4 blocks/CU (proven point) ============
// FROZEN. 60 VGPR + 64 AGPR acc = 124 regs = the 4-wave/SIMD budget exactly.
// Structure-space table (measured): 5blk/CU=spill(R8), 256^2-8phase(R7),
// coarse-pipe(R4), BK32-dbuf(R6), tile-queue(R5) -- all regressed vs this.
template<int KTOT, int ACT, bool RES>
__global__ __launch_bounds__(256, 4) void gemm_kernel(
    const ushort_t* __restrict__ A, const ushort_t* __restrict__ W,
    const float* __restrict__ bias,
    const ushort_t* __restrict__ resin, const float* __restrict__ resbias,
    ushort_t* __restrict__ out,
    int M, int Ntot, int T_in, int T_out, int sh1, int ncb)
{
  constexpr int AROW = (KTOT == 1024) ? 512 : KTOT;
  __shared__ ushort_t As[128 * 64];
  __shared__ ushort_t Ws[128 * 64];

  const int tid = threadIdx.x;
  const int lane = tid & 63;
  const int w = tid >> 6;
  const int wm = w >> 1, wn = w & 1;

  // XCD-chunked block swizzle (bijective, m204)
  const int nblocks = (int)gridDim.x;
  const int xcd = blockIdx.x & 7, kk = blockIdx.x >> 3;
  const int q = nblocks >> 3, rr = nblocks & 7;
  const int L = xcd * q + (xcd < rr ? xcd : rr) + kk;
  int rowblk, colblk;
  if (ncb == 4) { rowblk = L >> 2; colblk = L & 3; }
  else          { rowblk = L;      colblk = 0; }
  const int blockN = colblk * 128;
  const int blockRow = rowblk * 128;

  const int b0 = blockRow / T_out;
  const int t0 = blockRow - b0 * T_out;

  f32x4 acc[4][4];
#pragma unroll
  for (int i = 0; i < 4; ++i)
#pragma unroll
    for (int j = 0; j < 4; ++j) acc[i][j] = f32x4{0.f, 0.f, 0.f, 0.f};

  const int mloc = tid >> 3;
  const int csw = (((tid & 7) ^ ((tid >> 3) & 7))) * 8;  // T2 pre-swizzled src chunk

  for (int k0 = 0; k0 < KTOT; k0 += 64) {
    const int kcol = k0 & (AROW - 1);
    const int rowoff = (KTOT == 1024 && k0 >= 512) ? sh1 : 0;
#pragma unroll
    for (int j = 0; j < 4; ++j) {
      int m = j * 32 + mloc;
      int r = blockRow + m;
      int t = t0 + m;
      int bb = b0;
      if (t >= T_out) { ++bb; t -= T_out; }
      long grow = (r < M) ? ((long)bb * T_in + t + rowoff)
                          : ((long)b0 * T_in + t0 + rowoff);
      gload16(A + grow * AROW + kcol + csw, (char*)As + (j * 4096 + tid * 16));
    }
#pragma unroll
    for (int j = 0; j < 4; ++j) {
      int n = blockN + j * 32 + mloc;
      gload16(W + (long)n * KTOT + k0 + csw, (char*)Ws + (j * 4096 + tid * 16));
    }
    __syncthreads();
#pragma unroll
    for (int ks = 0; ks < 64; ks += 32) {
      short8 af[4], bf[4];
      const int hi = lane >> 4;
      const int rlo = lane & 15;
#pragma unroll
      for (int f = 0; f < 4; ++f) {
        int row = wm * 64 + f * 16 + rlo;
        int chunk = (ks >> 3) + hi;
        af[f] = *reinterpret_cast<const short8*>(
            (const char*)As + row * 128 + ((chunk ^ (row & 7)) << 4));
      }
#pragma unroll
      for (int f = 0; f < 4; ++f) {
        int row = wn * 64 + f * 16 + rlo;
        int chunk = (ks >> 3) + hi;
        bf[f] = *reinterpret_cast<const short8*>(
            (const char*)Ws + row * 128 + ((chunk ^ (row & 7)) << 4));
      }
#pragma unroll
      for (int fm = 0; fm < 4; ++fm)
#pragma unroll
        for (int fn = 0; fn < 4; ++fn)
          acc[fm][fn] = __builtin_amdgcn_mfma_f32_16x16x32_bf16(af[fm], bf[fn], acc[fm][fn], 0, 0, 0);
    }
    __syncthreads();
  }

  const int colb = lane & 15;
  const int rowb = (lane >> 4) * 4;
  float bv[4];
#pragma unroll
  for (int fn = 0; fn < 4; ++fn) {
    int col = blockN + wn * 64 + fn * 16 + colb;
    float b = bias ? bias[col] : 0.f;
    if (RES) b += resbias[col];
    bv[fn] = b;
  }
#pragma unroll
  for (int fm = 0; fm < 4; ++fm) {
#pragma unroll
    for (int reg = 0; reg < 4; ++reg) {
      int r = blockRow + wm * 64 + fm * 16 + rowb + reg;
      if (r < M) {
#pragma unroll
        for (int fn = 0; fn < 4; ++fn) {
          int col = blockN + wn * 64 + fn * 16 + colb;
          float v = acc[fm][fn][reg] + bv[fn];
          if (RES) v += bf2f(resin[(long)r * 512 + col]);
          if (ACT == 1) v = fmaxf(v, 0.f);
          else if (ACT == 2) v = tanhf(v);
          out[(long)r * Ntot + col] = f2bf(v);
        }
      }
    }
  }
}

// ============ fused bnf + s1, 64-row tiles (grid 782, 24 KB LDS) ============
__global__ __launch_bounds__(256, 4) void bnf_s1_kernel(
    const ushort_t* __restrict__ A, const ushort_t* __restrict__ Wb,
    const float* __restrict__ bb, const ushort_t* __restrict__ W1,
    ushort_t* __restrict__ outH, ushort_t* __restrict__ outS)
{
  __shared__ char smem[24576];

  const int tid = threadIdx.x;
  const int lane = tid & 63;
  const int w = tid >> 6;
  const int wm = w >> 1, wn = w & 1;
  const long blockRow = (long)blockIdx.x * 64;

  const int srow = tid >> 3;
  const int csw = (((tid & 7) ^ (srow & 7))) * 8;
  const int rlo = lane & 15, hi = lane >> 4;
  const int colb = lane & 15, rowb = (lane >> 4) * 4;

  f32x4 acc[2][4];
#pragma unroll
  for (int i = 0; i < 2; ++i)
#pragma unroll
    for (int j = 0; j < 4; ++j) acc[i][j] = f32x4{0.f, 0.f, 0.f, 0.f};

  for (int k0 = 0; k0 < 512; k0 += 64) {
#pragma unroll
    for (int i = 0; i < 2; ++i)
      gload16(A + (blockRow + i * 32 + srow) * 512 + k0 + csw,
              smem + i * 4096 + tid * 16);
#pragma unroll
    for (int j = 0; j < 4; ++j)
      gload16(Wb + (long)(j * 32 + srow) * 512 + k0 + csw,
              smem + 8192 + j * 4096 + tid * 16);
    __syncthreads();
#pragma unroll
    for (int ks = 0; ks < 64; ks += 32) {
      short8 af[2], bf[4];
#pragma unroll
      for (int f = 0; f < 2; ++f) {
        int row = wm * 32 + f * 16 + rlo;
        int chunk = (ks >> 3) + hi;
        af[f] = *reinterpret_cast<const short8*>(
            smem + row * 128 + ((chunk ^ (row & 7)) << 4));
      }
#pragma unroll
      for (int f = 0; f < 4; ++f) {
        int row = wn * 64 + f * 16 + rlo;
        int chunk = (ks >> 3) + hi;
        bf[f] = *reinterpret_cast<const short8*>(
            smem + 8192 + row * 128 + ((chunk ^ (row & 7)) << 4));
      }
#pragma unroll
      for (int fm = 0; fm < 2; ++fm)
#pragma unroll
        for (int fn = 0; fn < 4; ++fn)
          acc[fm][fn] = __builtin_amdgcn_mfma_f32_16x16x32_bf16(af[fm], bf[fn], acc[fm][fn], 0, 0, 0);
    }
    __syncthreads();
  }

#pragma unroll
  for (int fm = 0; fm < 2; ++fm) {
#pragma unroll
    for (int reg = 0; reg < 4; ++reg) {
      int rl = wm * 32 + fm * 16 + rowb + reg;
      long r = blockRow + rl;
#pragma unroll
      for (int fn = 0; fn < 4; ++fn) {
        int col = wn * 64 + fn * 16 + colb;
        float v = acc[fm][fn][reg] + bb[col];
        ushort_t us = f2bf(v);
        outH[r * 128 + col] = us;
        int ch = col >> 3;
        ((ushort_t*)(smem + rl * 256 + ((ch ^ (rl & 7)) << 4)))[col & 7] = us;
      }
    }
  }
  __syncthreads();

  f32x4 acc2[2][4];
#pragma unroll
  for (int i = 0; i < 2; ++i)
#pragma unroll
    for (int j = 0; j < 4; ++j) acc2[i][j] = f32x4{0.f, 0.f, 0.f, 0.f};
#pragma unroll
  for (int kt = 0; kt < 2; ++kt) {
#pragma unroll
    for (int ks = 0; ks < 64; ks += 32) {
      short8 af[2], bf[4];
#pragma unroll
      for (int f = 0; f < 2; ++f) {
        int row = wm * 32 + f * 16 + rlo;
        int ch = kt * 8 + (ks >> 3) + hi;
        af[f] = *reinterpret_cast<const short8*>(
            smem + row * 256 + ((ch ^ (row & 7)) << 4));
      }
#pragma unroll
      for (int f = 0; f < 4; ++f) {
        int row = wn * 64 + f * 16 + rlo;
        bf[f] = *reinterpret_cast<const short8*>(
            W1 + (long)row * 128 + kt * 64 + ks + hi * 8);
      }
#pragma unroll
      for (int fm = 0; fm < 2; ++fm)
#pragma unroll
        for (int fn = 0; fn < 4; ++fn)
          acc2[fm][fn] = __builtin_amdgcn_mfma_f32_16x16x32_bf16(af[fm], bf[fn], acc2[fm][fn], 0, 0, 0);
    }
  }
#pragma unroll
  for (int fm = 0; fm < 2; ++fm) {
#pragma unroll
    for (int reg = 0; reg < 4; ++reg) {
      long r = blockRow + wm * 32 + fm * 16 + rowb + reg;
#pragma unroll
      for (int fn = 0; fn < 4; ++fn) {
        int col = wn * 64 + fn * 16 + colb;
        outS[r * 128 + col] = f2bf(tanhf(acc2[fm][fn][reg]));
      }
    }
  }
}

// pad inner dim Kin -> 512 with zeros, f32 -> bf16. 8 elems/thread, 16B stores.
__global__ __launch_bounds__(256) void pad512_f32_kernel(
    const float* __restrict__ in, ushort_t* __restrict__ out, long total, int Kin)
{
  long g = ((long)blockIdx.x * 256 + threadIdx.x) * 8;
  if (g >= total) return;
  int r = (int)(g >> 9), c = (int)(g & 511);
  const float* src = in + (long)r * Kin + c;
  ushort_t o[8];
  if (c + 8 <= Kin) {
    float4 v0 = *(const float4*)(src);
    float4 v1 = *(const float4*)(src + 4);
    o[0] = f2bf(v0.x); o[1] = f2bf(v0.y); o[2] = f2bf(v0.z); o[3] = f2bf(v0.w);
    o[4] = f2bf(v1.x); o[5] = f2bf(v1.y); o[6] = f2bf(v1.z); o[7] = f2bf(v1.w);
  } else {
#pragma unroll
    for (int j = 0; j < 8; ++j)
      o[j] = (c + j < Kin) ? f2bf(src[j]) : (ushort_t)0;
  }
  short8 pk;
#pragma unroll
  for (int j = 0; j < 8; ++j) pk[j] = (short)o[j];
  *reinterpret_cast<short8*>(out + g) = pk;
}

// 3 TDNN repacks, one launch, coalesced both sides.
// kernel[o,i,s] f32 (strides 1024,2,1) -> W2[o, s*512+i] bf16.
// Thread (o, i0=8*ig) reads 64B contiguous (covers both taps for i0..i0+7),
// writes one 16B chunk per tap. 32768 threads/tensor = 128 blocks each.
__global__ __launch_bounds__(256) void repack3_kernel(
    const float* __restrict__ in0, const float* __restrict__ in1,
    const float* __restrict__ in2, ushort_t* __restrict__ out0,
    ushort_t* __restrict__ out1, ushort_t* __restrict__ out2)
{
  int which = blockIdx.x >> 7;
  int g = (blockIdx.x & 127) * 256 + threadIdx.x;   // 0..32767
  const float* in = (which == 0) ? in0 : (which == 1) ? in1 : in2;
  ushort_t* out = (which == 0) ? out0 : (which == 1) ? out1 : out2;
  int o = g >> 6, ig = g & 63;
  int i0 = ig * 8;
  const float* src = in + (long)o * 1024 + 2 * i0;
  float4 v[4];
#pragma unroll
  for (int q = 0; q < 4; ++q) v[q] = *(const float4*)(src + 4 * q);
  const float* vf = (const float*)v;
  short8 e, od;
#pragma unroll
  for (int j = 0; j < 8; ++j) {
    e[j]  = (short)f2bf(vf[2 * j]);       // s = 0
    od[j] = (short)f2bf(vf[2 * j + 1]);   // s = 1
  }
  *reinterpret_cast<short8*>(out + (long)o * 1024 + i0)       = e;
  *reinterpret_cast<short8*>(out + (long)o * 1024 + 512 + i0) = od;
}

// 10 f32->bf16 conversions in one launch; destinations contiguous in ws.
// 8 elems/thread, 16B stores. total = 2179072 elems -> 272384 thr = 1064 blocks.
__global__ __launch_bounds__(256) void multi_cvt_kernel(
    const float* __restrict__ s0, const float* __restrict__ s1,
    const float* __restrict__ s2, const float* __restrict__ s3,
    const float* __restrict__ s4, const float* __restrict__ s5,
    const float* __restrict__ s6, const float* __restrict__ s7,
    const float* __restrict__ s8, const float* __restrict__ s9,
    ushort_t* __restrict__ dst)
{
  long g8 = ((long)blockIdx.x * 256 + threadIdx.x) * 8;
  if (g8 >= 2179072) return;
  const float* src; long off;
  if (g8 < 8L * 262144) {
    int seg = (int)(g8 >> 18); off = g8 & 262143;
    switch (seg) {
      case 0: src = s0; break; case 1: src = s1; break;
      case 2: src = s2; break; case 3: src = s3; break;
      case 4: src = s4; break; case 5: src = s5; break;
      case 6: src = s6; break; default: src = s7; break;
    }
  } else if (g8 < 8L * 262144 + 65536) { src = s8; off = g8 - 8L * 262144; }
  else { src = s9; off = g8 - (8L * 262144 + 65536); }
  float4 v0 = *(const float4*)(src + off);
  float4 v1 = *(const float4*)(src + off + 4);
  short8 pk;
  pk[0] = (short)f2bf(v0.x); pk[1] = (short)f2bf(v0.y);
  pk[2] = (short)f2bf(v0.z); pk[3] = (short)f2bf(v0.w);
  pk[4] = (short)f2bf(v1.x); pk[5] = (short)f2bf(v1.y);
  pk[6] = (short)f2bf(v1.z); pk[7] = (short)f2bf(v1.w);
  *reinterpret_cast<short8*>(dst + g8) = pk;
}

// one block per (batch, head): scores -> softmax over t -> At (f32)
__global__ __launch_bounds__(256) void attn_kernel(
    const ushort_t* __restrict__ s1, const float* __restrict__ ws2,
    float* __restrict__ At_out, int T)
{
  __shared__ float sc[800];
  __shared__ float w2s[128];
  __shared__ float redm[4], reds[4];
  const int b = blockIdx.x / 5, h = blockIdx.x % 5;
  const int tid = threadIdx.x;
  const int lane = tid & 63, wv = tid >> 6;
  if (tid < 128) w2s[tid] = ws2[h * 128 + tid];
  __syncthreads();
  for (int t = tid; t < T; t += 256) {
    const ushort_t* row = s1 + ((long)b * T + t) * 128;
    float a = 0.f;
    for (int c = 0; c < 128; c += 8) {
      short8 v = *reinterpret_cast<const short8*>(row + c);
#pragma unroll
      for (int j = 0; j < 8; ++j) a += bf2f((unsigned short)v[j]) * w2s[c + j];
    }
    sc[t] = a;
  }
  __syncthreads();
  float m = -1e30f;
  for (int t = tid; t < T; t += 256) m = fmaxf(m, sc[t]);
#pragma unroll
  for (int off = 32; off > 0; off >>= 1) m = fmaxf(m, __shfl_xor(m, off));
  if (lane == 0) redm[wv] = m;
  __syncthreads();
  m = fmaxf(fmaxf(redm[0], redm[1]), fmaxf(redm[2], redm[3]));
  float s = 0.f;
  for (int t = tid; t < T; t += 256) s += expf(sc[t] - m);
#pragma unroll
  for (int off = 32; off > 0; off >>= 1) s += __shfl_xor(s, off);
  if (lane == 0) reds[wv] = s;
  __syncthreads();
  s = reds[0] + reds[1] + reds[2] + reds[3];
  float inv = 1.f / s;
  long base = ((long)b * 5 + h) * T;
  for (int t = tid; t < T; t += 256)
    At_out[base + t] = expf(sc[t] - m) * inv;
}

// pool stage 1: partial sums over 64-t chunks (13*64 blocks)
__global__ __launch_bounds__(640) void pool_partial_kernel(
    const float* __restrict__ At_f, const ushort_t* __restrict__ hb,
    float* __restrict__ part, int T)
{
  int c = blockIdx.x >> 6;
  int b = blockIdx.x & 63;
  int tid = threadIdx.x;
  int h = tid >> 7, d = tid & 127;
  int t0 = c * 64;
  int t1 = t0 + 64; if (t1 > T) t1 = T;
  const float* at = At_f + ((long)b * 5 + h) * T;
  const ushort_t* hr = hb + (long)b * T * 128 + d;
  float acc = 0.f;
  int t = t0;
  for (; t + 4 <= t1; t += 4) {
    acc += at[t]     * bf2f(hr[(long)(t) * 128]);
    acc += at[t + 1] * bf2f(hr[(long)(t + 1) * 128]);
    acc += at[t + 2] * bf2f(hr[(long)(t + 2) * 128]);
    acc += at[t + 3] * bf2f(hr[(long)(t + 3) * 128]);
  }
  for (; t < t1; ++t) acc += at[t] * bf2f(hr[(long)t * 128]);
  part[((long)c * 64 + b) * 640 + tid] = acc;
}

// pool stage 2: fixed-order deterministic reduce
__global__ __launch_bounds__(640) void pool_reduce_kernel(
    const float* __restrict__ part, float* __restrict__ pooled, int nc)
{
  int b = blockIdx.x, tid = threadIdx.x;
  float s = 0.f;
  for (int c = 0; c < nc; ++c) s += part[((long)c * 64 + b) * 640 + tid];
  pooled[b * 640 + tid] = s;
}

// out[b,o] = relu( pooled[b,:].bnw_w[o,:] + bnw_b[o] ); 4 lanes per o.
__global__ __launch_bounds__(512) void head_kernel(
    const float* __restrict__ pooled, const float* __restrict__ w,
    const float* __restrict__ bias, float* __restrict__ out)
{
  int b = blockIdx.x;
  int o = threadIdx.x >> 2;
  int part = threadIdx.x & 3;
  const float* wr = w + o * 640 + part * 160;
  const float* p = pooled + b * 640 + part * 160;
  float acc = 0.f;
#pragma unroll 4
  for (int i = 0; i < 160; i += 4)
    acc += p[i] * wr[i] + p[i + 1] * wr[i + 1] +
           p[i + 2] * wr[i + 2] + p[i + 3] * wr[i + 3];
  acc += __shfl_xor(acc, 1);
  acc += __shfl_xor(acc, 2);
  if (part == 0) out[b * 128 + o] = fmaxf(acc + bias[o], 0.f);
}

extern "C" void kernel_launch(void* const* d_in, const int* in_sizes, int n_in,
                              void* d_out, int out_size, void* d_ws, size_t ws_size,
                              hipStream_t stream)
{
  (void)in_sizes; (void)n_in; (void)out_size; (void)ws_size;
  const float* x     = (const float*)d_in[0];
  const float* fc1_w = (const float*)d_in[1];
  const float* fc1_b = (const float*)d_in[2];
  const float *rw1[4], *rb1[4], *rw2[4], *rb2[4], *rbias[4];
  for (int i = 0; i < 4; ++i) {
    rw1[i]   = (const float*)d_in[3 + 5 * i + 0];
    rb1[i]   = (const float*)d_in[3 + 5 * i + 1];
    rw2[i]   = (const float*)d_in[3 + 5 * i + 2];
    rb2[i]   = (const float*)d_in[3 + 5 * i + 3];
    rbias[i] = (const float*)d_in[3 + 5 * i + 4];
  }
  const float *tk[3], *tb[3];
  for (int i = 0; i < 3; ++i) {
    tk[i] = (const float*)d_in[23 + 2 * i];
    tb[i] = (const float*)d_in[24 + 2 * i];
  }
  const float* bnf_w = (const float*)d_in[29];
  const float* bnf_b = (const float*)d_in[30];
  const float* ws1   = (const float*)d_in[31];
  const float* ws2   = (const float*)d_in[32];
  const float* bnw_w = (const float*)d_in[33];
  const float* bnw_b = (const float*)d_in[34];

  char* ws = (char*)d_ws;
  const size_t SZBUF = (size_t)51200 * 512 * 2;
  ushort_t* bufA = (ushort_t*)(ws);
  ushort_t* bufB = (ushort_t*)(ws + SZBUF);
  ushort_t* bufC = (ushort_t*)(ws + 2 * SZBUF);
  ushort_t* wfc1 = (ushort_t*)(ws + 3 * SZBUF);
  ushort_t* w2[3];
  w2[0] = wfc1 + 512 * 512;
  w2[1] = w2[0] + 512 * 1024;
  w2[2] = w2[1] + 512 * 1024;
  ushort_t* rwc[8];
  rwc[0] = w2[2] + 512 * 1024;
  for (int i = 1; i < 8; ++i) rwc[i] = rwc[i - 1] + 512 * 512;
  ushort_t* bnfwc = rwc[7] + 512 * 512;
  ushort_t* ws1c  = bnfwc + 128 * 512;
  float* pooled   = (float*)(ws1c + 128 * 128);
  float* part     = pooled + 64 * 640;         // [13][64][640] f32

  float* out_f = (float*)d_out;
  float* At_f  = out_f + 8192;

  dim3 blk(256);
  // ---- weight/input prep (f32 -> bf16), 4 launches ----
  {
    long totalx = (long)51200 * 512;
    pad512_f32_kernel<<<dim3((unsigned)((totalx / 8 + 255) / 256)), blk, 0, stream>>>(x, bufA, totalx, 500);
    long totalw = (long)512 * 512;
    pad512_f32_kernel<<<dim3((unsigned)((totalw / 8 + 255) / 256)), blk, 0, stream>>>(fc1_w, wfc1, totalw, 500);
    repack3_kernel<<<dim3(384), blk, 0, stream>>>(tk[0], tk[1], tk[2], w2[0], w2[1], w2[2]);
    multi_cvt_kernel<<<dim3(1064), blk, 0, stream>>>(
        rw1[0], rw2[0], rw1[1], rw2[1], rw1[2], rw2[2], rw1[3], rw2[3],
        bnf_w, ws1, rwc[0]);
  }
  // ---- fc1 (M=51200, K=512pad) ----
  gemm_kernel<512, 1, false><<<dim3(1600), blk, 0, stream>>>(bufA, wfc1, fc1_b, nullptr, nullptr, bufB, 51200, 512, 51200, 51200, 0, 4);
  // ---- res1 ----
  gemm_kernel<512, 1, false><<<dim3(1600), blk, 0, stream>>>(bufB, rwc[0], rb1[0], nullptr, nullptr, bufC, 51200, 512, 51200, 51200, 0, 4);
  gemm_kernel<512, 1, true ><<<dim3(1600), blk, 0, stream>>>(bufC, rwc[1], rb2[0], bufB, rbias[0], bufA, 51200, 512, 51200, 51200, 0, 4);
  // ---- tdnn2 (800 -> 797, sh1=3) ----
  gemm_kernel<1024, 1, false><<<dim3(1596), blk, 0, stream>>>(bufA, w2[0], tb[0], nullptr, nullptr, bufB, 51008, 512, 800, 797, 3, 4);
  // ---- res2 ----
  gemm_kernel<512, 1, false><<<dim3(1596), blk, 0, stream>>>(bufB, rwc[2], rb1[1], nullptr, nullptr, bufC, 51008, 512, 51008, 51008, 0, 4);
  gemm_kernel<512, 1, true ><<<dim3(1596), blk, 0, stream>>>(bufC, rwc[3], rb2[1], bufB, rbias[1], bufA, 51008, 512, 51008, 51008, 0, 4);
  // ---- tdnn3 (797 -> 791, sh1=6) ----
  gemm_kernel<1024, 1, false><<<dim3(1584), blk, 0, stream>>>(bufA, w2[1], tb[1], nullptr, nullptr, bufB, 50624, 512, 797, 791, 6, 4);
  // ---- res3 ----
  gemm_kernel<512, 1, false><<<dim3(1584), blk, 0, stream>>>(bufB, rwc[4], rb1[2], nullptr, nullptr, bufC, 50624, 512, 50624, 50624, 0, 4);
  gemm_kernel<512, 1, true ><<<dim3(1584), blk, 0, stream>>>(bufC, rwc[5], rb2[2], bufB, rbias[2], bufA, 50624, 512, 50624, 50624, 0, 4);
  // ---- tdnn4 (791 -> 782, sh1=9) ----
  gemm_kernel<1024, 1, false><<<dim3(1564), blk, 0, stream>>>(bufA, w2[2], tb[2], nullptr, nullptr, bufB, 50048, 512, 791, 782, 9, 4);
  // ---- res4 ----
  gemm_kernel<512, 1, false><<<dim3(1564), blk, 0, stream>>>(bufB, rwc[6], rb1[3], nullptr, nullptr, bufC, 50048, 512, 50048, 50048, 0, 4);
  gemm_kernel<512, 1, true ><<<dim3(1564), blk, 0, stream>>>(bufC, rwc[7], rb2[3], bufB, rbias[3], bufA, 50048, 512, 50048, 50048, 0, 4);
  // ---- fused bnf + s1 (64-row tiles: 50048/64 = 782 blocks) ----
  bnf_s1_kernel<<<dim3(782), blk, 0, stream>>>(bufA, bnfwc, bnf_b, ws1c, bufB, bufC);
  // ---- attention softmax -> At (one block per (b,h)) ----
  attn_kernel<<<dim3(320), blk, 0, stream>>>(bufC, ws2, At_f, 782);
  // ---- pooled = At @ hbnf, two-stage (13 chunks of 64 t) ----
  pool_partial_kernel<<<dim3(13 * 64), dim3(640), 0, stream>>>(At_f, bufB, part, 782);
  pool_reduce_kernel<<<dim3(64), dim3(640), 0, stream>>>(part, pooled, 13);
  // ---- head ----
  head_kernel<<<dim3(64), dim3(512), 0, stream>>>(pooled, bnw_w, bnw_b, out_f);
}